// Round 3
// baseline (447.511 us; speedup 1.0000x reference)
//
#include <hip/hip_runtime.h>

// SOAM fused pipeline v4, MI355X gfx950. Change vs v3: occupancy was register-bound,
// not LDS-bound (v3 halved LDS, occupancy stayed 19.5% => total VGPR+AGPR ~256 => 2
// waves/SIMD). v4 halves per-wave state: j-tile 64 -> 32, grid 2048 -> 4096. Accumulator
// arrays drop 64->32 regs each (c2r[2][4], accT[4][2], acc2[2][4]); peak live ~120 =>
// __launch_bounds__(256,4) targets 4 waves/SIMD = 4 blocks/CU (50% occupancy). Wave
// ownership invariants identical to v3 (wave = band; T' rows wave-own; same 3 barriers).
// HBM traffic unchanged; Ssum re-reads double but are L2-resident (128KB/batch).
// B=8, C=64, H=W=256. Identity: R1==R2 => R3+R4 = (S1+S2)@R. Permutations
// i'=(i&3)*64+(i>>2), k^=(k&3)*64+(k>>2) applied to Ssum when writing it.
// ws: C1 fp32 [0,2M) | G fp32 [2M,6M) | Ssum2 bf16 [6M,7M).

#define EPS 1e-5f

typedef __attribute__((ext_vector_type(8))) short bf16x8;
typedef __attribute__((ext_vector_type(4))) float f32x4;

__device__ __forceinline__ unsigned short f2bf(float f){
  union { float f; unsigned int u; } a; a.f = f;
  return (unsigned short)((a.u + 0x7fffu + ((a.u >> 16) & 1u)) >> 16);
}
__device__ __forceinline__ float lrelu(float y){ return y >= 0.f ? y : 0.2f * y; }
__device__ __forceinline__ bf16x8 cvt8(const float* p){
  float4 a = *(const float4*)p;
  float4 b = *(const float4*)(p + 4);
  bf16x8 r;
  r[0] = (short)f2bf(a.x); r[1] = (short)f2bf(a.y); r[2] = (short)f2bf(a.z); r[3] = (short)f2bf(a.w);
  r[4] = (short)f2bf(b.x); r[5] = (short)f2bf(b.y); r[6] = (short)f2bf(b.z); r[7] = (short)f2bf(b.w);
  return r;
}

// ---------------- K1: C1 = lrelu(BN(x . w1)) only, pure streaming ----------------
__global__ __launch_bounds__(256) void k1_c1(
    const float* __restrict__ x, const float* __restrict__ w1,
    const float* __restrict__ pb1, const float* __restrict__ pg1,
    const float* __restrict__ pbe1, const float* __restrict__ pm1,
    const float* __restrict__ pv1,
    float* __restrict__ C1)
{
  const int blk = blockIdx.x;
  const int b = blk >> 6;
  const int n0 = (blk & 63) << 10;
  const int t = threadIdx.x;
  __shared__ float w1s[64];
  if (t < 64) w1s[t] = w1[t];
  __syncthreads();
  const float* xb = x + ((size_t)b << 22);
  const int n = n0 + (t << 2);
  float4 d = {0.f, 0.f, 0.f, 0.f};
  #pragma unroll 16
  for (int c = 0; c < 64; c++){
    const float4 xv = *(const float4*)(xb + ((size_t)c << 16) + n);
    const float wv = w1s[c];
    d.x = fmaf(xv.x, wv, d.x); d.y = fmaf(xv.y, wv, d.y);
    d.z = fmaf(xv.z, wv, d.z); d.w = fmaf(xv.w, wv, d.w);
  }
  const float s1 = pg1[0] * rsqrtf(pv1[0] + EPS);
  const float t1 = (pb1[0] - pm1[0]) * s1 + pbe1[0];
  float4 o;
  o.x = lrelu(d.x * s1 + t1); o.y = lrelu(d.y * s1 + t1);
  o.z = lrelu(d.z * s1 + t1); o.w = lrelu(d.w * s1 + t1);
  *(float4*)(C1 + (b << 16) + n) = o;
}

// ---------------- K2a: Gram matrices G1 = C1 C1^T (rows), G2 = C1^T C1 (cols), fp32 ----------------
__global__ __launch_bounds__(256) void k2_gram(const float* __restrict__ C1, float* __restrict__ G)
{
  const int bx = blockIdx.x;
  const int b = bx >> 5;
  const int which = (bx >> 4) & 1;
  const int tile = bx & 15;
  const int i0 = (tile >> 2) << 6, j0 = (tile & 3) << 6;
  const float* Cb = C1 + (b << 16);
  __shared__ float Al[32][68];
  __shared__ float Bl[32][68];
  const int t = threadIdx.x;
  const int tx = t & 15, ty = t >> 4;
  float acc[4][4];
  #pragma unroll
  for (int i = 0; i < 4; i++)
    #pragma unroll
    for (int j = 0; j < 4; j++) acc[i][j] = 0.f;

  for (int kc = 0; kc < 8; kc++){
    const int k0 = kc << 5;
    __syncthreads();
    if (which == 0){
      const int i = t & 63, kq = t >> 6;
      const float* pa = Cb + (i0 + i)*256 + k0 + kq*8;
      const float* pb = Cb + (j0 + i)*256 + k0 + kq*8;
      #pragma unroll
      for (int u = 0; u < 8; u++){ Al[kq*8+u][i] = pa[u]; Bl[kq*8+u][i] = pb[u]; }
    } else {
      const int k = t >> 3, i8 = (t & 7) << 3;
      const float* pa = Cb + (k0 + k)*256 + i0 + i8;
      const float* pb = Cb + (k0 + k)*256 + j0 + i8;
      *(float4*)&Al[k][i8]   = *(const float4*)pa;
      *(float4*)&Al[k][i8+4] = *(const float4*)(pa+4);
      *(float4*)&Bl[k][i8]   = *(const float4*)pb;
      *(float4*)&Bl[k][i8+4] = *(const float4*)(pb+4);
    }
    __syncthreads();
    #pragma unroll 4
    for (int k = 0; k < 32; k++){
      float4 a4 = *(const float4*)&Al[k][ty << 2];
      float4 b4 = *(const float4*)&Bl[k][tx << 2];
      float av[4] = {a4.x, a4.y, a4.z, a4.w};
      float bw[4] = {b4.x, b4.y, b4.z, b4.w};
      #pragma unroll
      for (int ii = 0; ii < 4; ii++)
        #pragma unroll
        for (int jj = 0; jj < 4; jj++)
          acc[ii][jj] = fmaf(av[ii], bw[jj], acc[ii][jj]);
    }
  }
  float* Go = G + ((size_t)(which*8 + b) << 16);
  #pragma unroll
  for (int r = 0; r < 4; r++){
    float4 o4 = {acc[r][0], acc[r][1], acc[r][2], acc[r][3]};
    *(float4*)&Go[(i0 + (ty<<2) + r)*256 + j0 + (tx<<2)] = o4;
  }
}

// ---------------- K2b: row softmax of G1,G2 -> S1,S2 (fp32, d_out) + permuted Ssum (bf16, ws) ----------------
__global__ __launch_bounds__(256) void k2_softmax(const float* __restrict__ G,
    float* __restrict__ S1o, float* __restrict__ S2o,
    unsigned short* __restrict__ Ssum2)
{
  const int bx = blockIdx.x;
  const int b = bx >> 8, i = bx & 255;
  const int j = threadIdx.x;
  const float v1 = G[((size_t)b << 16) + i*256 + j];
  const float v2 = G[((size_t)(8 + b) << 16) + i*256 + j];
  __shared__ float sm[4], sm2[4], ss[4], ss2[4];
  float a1 = v1, a2 = v2;
  #pragma unroll
  for (int off = 32; off > 0; off >>= 1){
    a1 = fmaxf(a1, __shfl_xor(a1, off));
    a2 = fmaxf(a2, __shfl_xor(a2, off));
  }
  const int wv = j >> 6;
  if ((j & 63) == 0){ sm[wv] = a1; sm2[wv] = a2; }
  __syncthreads();
  const float m1v = fmaxf(fmaxf(sm[0], sm[1]), fmaxf(sm[2], sm[3]));
  const float m2v = fmaxf(fmaxf(sm2[0], sm2[1]), fmaxf(sm2[2], sm2[3]));
  float e1 = __expf(v1 - m1v), e2 = __expf(v2 - m2v);
  float s1 = e1, s2 = e2;
  #pragma unroll
  for (int off = 32; off > 0; off >>= 1){
    s1 += __shfl_xor(s1, off);
    s2 += __shfl_xor(s2, off);
  }
  if ((j & 63) == 0){ ss[wv] = s1; ss2[wv] = s2; }
  __syncthreads();
  const float d1 = ss[0]+ss[1]+ss[2]+ss[3];
  const float d2 = ss2[0]+ss2[1]+ss2[2]+ss2[3];
  const float S1v = e1 / d1, S2v = e2 / d2;
  S1o[((size_t)b << 16) + i*256 + j] = S1v;
  S2o[((size_t)b << 16) + i*256 + j] = S2v;
  const int ip = ((i & 3) << 6) | (i >> 2);
  const int kp = ((j & 3) << 6) | (j >> 2);
  Ssum2[((size_t)b << 16) + ip*256 + kp] = f2bf(S1v + S2v);
}

// ---------------- K3: stage x -> recompute C2 (MFMA, in-LDS) -> T' = Ssum2 @ R -> convO -> out ----------------
// grid 4096 (b*512 + jtile32), block 256, wave = band (32 j-positions each).
// Single LDS buffer XL (18KB): x (bf16 [s][c]) -> C2 (wave-own rows) -> barrier ->
// GEMM1 operand -> barrier -> T' (wave-own rows) -> GEMM2 operand.
// fp32 C2 residual in registers (MFMA1 D-layout == epilogue layout, lane-exact).
__global__ __launch_bounds__(256, 4) void k3_main(
    const float* __restrict__ x,
    const float* __restrict__ wA, const float* __restrict__ pbA,
    const float* __restrict__ pgA, const float* __restrict__ pbeA,
    const float* __restrict__ pmA, const float* __restrict__ pvA,
    const unsigned short* __restrict__ Ssum2,
    const float* __restrict__ wO, const float* __restrict__ pbO,
    const float* __restrict__ pgO, const float* __restrict__ pbeO,
    const float* __restrict__ pmO, const float* __restrict__ pvO,
    float* __restrict__ out)
{
  __shared__ unsigned short XL[128][72];   // bf16 [s = band*32 + jl][c], +8 pad
  __shared__ float sAl[64], tAl[64], sOl[64], tOl[64];
  const int blk = blockIdx.x;
  const int b  = blk >> 9;
  const int j0 = (blk & 511) << 5;
  const int t = threadIdx.x;
  const int lane = t & 63, wv = t >> 6;
  const int m = lane & 15, q = lane >> 4;

  if (t < 64){
    const float sA = pgA[t] * rsqrtf(pvA[t] + EPS);
    sAl[t] = sA; tAl[t] = (pbA[t] - pmA[t]) * sA + pbeA[t];
    const float sO = pgO[t] * rsqrtf(pvO[t] + EPS);
    sOl[t] = sO; tOl[t] = (pbO[t] - pmO[t]) * sO + pbeO[t];
  }

  // ---- stage x strip (wave-own rows): lane = channel, 8 x dwordx4 per thread ----
  // wave wv = band wv: global positions (wv<<14) + j0 .. +31; rows 32wv..32wv+31.
  {
    const float* xs = x + ((size_t)b << 22) + ((size_t)lane << 16) + (wv << 14) + j0;
    #pragma unroll
    for (int i = 0; i < 8; i++){
      const float4 xv = *(const float4*)(xs + 4*i);
      const int s = 32*wv + 4*i;
      XL[s+0][lane] = f2bf(xv.x);
      XL[s+1][lane] = f2bf(xv.y);
      XL[s+2][lane] = f2bf(xv.z);
      XL[s+3][lane] = f2bf(xv.w);
    }
  }
  __syncthreads();   // publishes sAl/tAl/sOl/tOl (x rows are wave-own anyway)

  float sAv[4], tAv[4];
  #pragma unroll
  for (int ot = 0; ot < 4; ot++){ sAv[ot] = sAl[16*ot + m]; tAv[ot] = tAl[16*ot + m]; }

  // wA B-frags: wA[o][c] fp32 -> bf16, lane col = o-local (m), 8 consecutive c
  bf16x8 wfrA[4][2];
  #pragma unroll
  for (int ot = 0; ot < 4; ot++)
    #pragma unroll
    for (int ks = 0; ks < 2; ks++)
      wfrA[ot][ks] = cvt8(wA + (16*ot + m)*64 + ks*32 + q*8);

  const f32x4 vzero = {0.f, 0.f, 0.f, 0.f};
  f32x4 c2r[2][4];   // [nt][ot] — fp32 C2 residual, held to the epilogue (32 regs)
  #pragma unroll
  for (int i = 0; i < 2; i++)
    #pragma unroll
    for (int j = 0; j < 4; j++) c2r[i][j] = vzero;

  // MFMA1: A-frags straight from XL (ds_read_b128); wave-own rows 32wv + 16nt + m
  #pragma unroll
  for (int ks = 0; ks < 2; ks++)
    #pragma unroll
    for (int nt = 0; nt < 2; nt++){
      const bf16x8 af = *(const bf16x8*)&XL[32*wv + 16*nt + m][ks*32 + q*8];
      #pragma unroll
      for (int ot = 0; ot < 4; ot++)
        c2r[nt][ot] = __builtin_amdgcn_mfma_f32_16x16x32_bf16(af, wfrA[ot][ks], c2r[nt][ot], 0, 0, 0);
    }

  // BN + LReLU (fp32 residual) + bf16 C2 into XL (overwrites x; wave-own rows,
  // ordered by the MFMA data dependency on the fragment reads of the same row group).
  #pragma unroll
  for (int nt = 0; nt < 2; nt++)
    #pragma unroll
    for (int ot = 0; ot < 4; ot++){
      #pragma unroll
      for (int r = 0; r < 4; r++){
        const float v = lrelu(c2r[nt][ot][r] * sAv[ot] + tAv[ot]);
        c2r[nt][ot][r] = v;
        XL[32*wv + 16*nt + 4*q + r][16*ot + m] = f2bf(v);
      }
    }
  __syncthreads();   // all C2 rows visible to all waves

  // GEMM1: T'[i'][j] = sum_k^ Ssum2[i'][k^] * XL[(k^>>6)*32 + jl][k^&63]
  // wave wv owns i' rows 64wv..64wv+63 (i' group == band), jl 0..31.
  const unsigned short* Sb = Ssum2 + ((size_t)b << 16);
  f32x4 accT[4][2];   // [it][jt] (32 regs)
  #pragma unroll
  for (int i = 0; i < 4; i++)
    #pragma unroll
    for (int j = 0; j < 2; j++) accT[i][j] = vzero;

  #pragma unroll
  for (int ks = 0; ks < 8; ks++){
    const int kk = ks*32 + q*8;
    const int rk = kk >> 6;
    const int c0 = kk & 63;
    bf16x8 af[4], bv[2];
    #pragma unroll
    for (int it = 0; it < 4; it++)
      af[it] = *(const bf16x8*)(Sb + (64*wv + 16*it + m)*256 + kk);
    #pragma unroll
    for (int jt = 0; jt < 2; jt++)
      bv[jt] = *(const bf16x8*)&XL[(rk << 5) + 16*jt + m][c0];
    #pragma unroll
    for (int it = 0; it < 4; it++)
      #pragma unroll
      for (int jt = 0; jt < 2; jt++)
        accT[it][jt] = __builtin_amdgcn_mfma_f32_16x16x32_bf16(af[it], bv[jt], accT[it][jt], 0, 0, 0);
  }
  __syncthreads();   // all waves done reading C2 before T' overwrites XL

  // T' -> XL wave-own rows [32wv + jl][c' = i'_local]; GEMM2 (same wave) reads back.
  #pragma unroll
  for (int it = 0; it < 4; it++)
    #pragma unroll
    for (int jt = 0; jt < 2; jt++){
      uint2 pk;
      pk.x = (unsigned)f2bf(accT[it][jt][0]) | ((unsigned)f2bf(accT[it][jt][1]) << 16);
      pk.y = (unsigned)f2bf(accT[it][jt][2]) | ((unsigned)f2bf(accT[it][jt][3]) << 16);
      *(uint2*)&XL[32*wv + 16*jt + m][16*it + 4*q] = pk;
    }

  // GEMM2: out_pre[s][cout] = sum_c' T[s][c'] * wO[cout][c']
  bf16x8 wfrO[4][2];
  #pragma unroll
  for (int ct = 0; ct < 4; ct++)
    #pragma unroll
    for (int k2 = 0; k2 < 2; k2++)
      wfrO[ct][k2] = cvt8(wO + (16*ct + m)*64 + k2*32 + q*8);

  f32x4 acc2[2][4];
  #pragma unroll
  for (int i = 0; i < 2; i++)
    #pragma unroll
    for (int j = 0; j < 4; j++) acc2[i][j] = vzero;

  #pragma unroll
  for (int k2 = 0; k2 < 2; k2++)
    #pragma unroll
    for (int stl = 0; stl < 2; stl++){
      const bf16x8 afT = *(const bf16x8*)&XL[32*wv + 16*stl + m][k2*32 + q*8];
      #pragma unroll
      for (int ct = 0; ct < 4; ct++)
        acc2[stl][ct] = __builtin_amdgcn_mfma_f32_16x16x32_bf16(afT, wfrO[ct][k2], acc2[stl][ct], 0, 0, 0);
    }

  float sOv[4], tOv[4];
  #pragma unroll
  for (int ct = 0; ct < 4; ct++){ sOv[ct] = sOl[16*ct + m]; tOv[ct] = tOl[16*ct + m]; }

  // epilogue: out = C2 (regs) + lrelu(BN_O(acc2)); pure coalesced float4 store
  const size_t outB = ((size_t)b << 22);
  #pragma unroll
  for (int stl = 0; stl < 2; stl++)
    #pragma unroll
    for (int ct = 0; ct < 4; ct++){
      const int cout = 16*ct + m;
      const int ng0 = (wv << 14) + j0 + 16*stl + 4*q;
      float* po = out + outB + ((size_t)cout << 16) + ng0;
      float4 pk;
      pk.x = c2r[stl][ct][0] + lrelu(acc2[stl][ct][0] * sOv[ct] + tOv[ct]);
      pk.y = c2r[stl][ct][1] + lrelu(acc2[stl][ct][1] * sOv[ct] + tOv[ct]);
      pk.z = c2r[stl][ct][2] + lrelu(acc2[stl][ct][2] * sOv[ct] + tOv[ct]);
      pk.w = c2r[stl][ct][3] + lrelu(acc2[stl][ct][3] * sOv[ct] + tOv[ct]);
      *(float4*)po = pk;
    }
}

extern "C" void kernel_launch(void* const* d_in, const int* in_sizes, int n_in,
                              void* d_out, int out_size, void* d_ws, size_t ws_size,
                              hipStream_t stream) {
  const float* x   = (const float*)d_in[0];
  const float* w1  = (const float*)d_in[1];
  const float* b1  = (const float*)d_in[2];
  const float* g1  = (const float*)d_in[3];
  const float* be1 = (const float*)d_in[4];
  const float* m1  = (const float*)d_in[5];
  const float* v1  = (const float*)d_in[6];
  const float* wA  = (const float*)d_in[7];
  const float* bA  = (const float*)d_in[8];
  const float* gA  = (const float*)d_in[9];
  const float* beA = (const float*)d_in[10];
  const float* mA  = (const float*)d_in[11];
  const float* vA  = (const float*)d_in[12];
  const float* wO  = (const float*)d_in[13];
  const float* bO  = (const float*)d_in[14];
  const float* gO  = (const float*)d_in[15];
  const float* beO = (const float*)d_in[16];
  const float* mO  = (const float*)d_in[17];
  const float* vO  = (const float*)d_in[18];

  float* out = (float*)d_out;

  // ws layout (bytes): C1 fp32 [0,2M) | G fp32 [2M,6M) | Ssum2 bf16 [6M,7M)
  char* ws = (char*)d_ws;
  float* C1             = (float*)(ws);
  float* G              = (float*)(ws + (size_t)(2u << 20));
  unsigned short* Ssum2 = (unsigned short*)(ws + (size_t)(6u << 20));

  k1_c1<<<dim3(512), dim3(256), 0, stream>>>(x, w1, b1, g1, be1, m1, v1, C1);
  k2_gram<<<dim3(256), dim3(256), 0, stream>>>(C1, G);
  k2_softmax<<<dim3(2048), dim3(256), 0, stream>>>(G, out + 33554432u, out + 34078720u, Ssum2);
  k3_main<<<dim3(4096), dim3(256), 0, stream>>>(x, wA, bA, gA, beA, mA, vA, Ssum2,
                                                wO, bO, gO, beO, mO, vO, out);
}

// Round 4
// 433.259 us; speedup vs baseline: 1.0329x; 1.0329x over previous
//
#include <hip/hip_runtime.h>

// SOAM fused pipeline v5, MI355X gfx950.
// Post-mortem v4: __launch_bounds__(256,4) forced a 128-reg total budget; GEMM1 peak live
// state (~150) spilled to scratch -> +137MB HBM traffic (WRITE 139->239MB, FETCH 74->111MB)
// and dur regressed 108->172us. v5 keeps v4's small per-wave state (c2r[2][4], accT[4][2],
// acc2[2][4]; no spills at 168 regs) but restores v3's per-block 64-col footprint (its
// near-ideal FETCH/WRITE) via 512-thread blocks: 8 waves = (quarter, col-half), launch_bounds
// (512,3) -> 3 blocks/CU = 24 waves/CU (3x v3's residency). Same 3 barriers; wave-own rows:
// wave wv owns XL rows 32wv..32wv+31 in every phase.
// Also: k2_gram K-split 4 (1024 blocks, 4/CU) with fp32 partials staged in d_out[0,16MB)
// (free until k3 overwrites); k2_softmax sums the 4 partials.
// B=8, C=64, H=W=256. Identity: R1==R2 => R3+R4 = (S1+S2)@R. Permutations
// i'=(i&3)*64+(i>>2), k^=(k&3)*64+(k>>2) applied to Ssum when writing it.
// ws: C1 fp32 [0,2M) | (unused) | Ssum2 bf16 [6M,7M).

#define EPS 1e-5f

typedef __attribute__((ext_vector_type(8))) short bf16x8;
typedef __attribute__((ext_vector_type(4))) float f32x4;

__device__ __forceinline__ unsigned short f2bf(float f){
  union { float f; unsigned int u; } a; a.f = f;
  return (unsigned short)((a.u + 0x7fffu + ((a.u >> 16) & 1u)) >> 16);
}
__device__ __forceinline__ float lrelu(float y){ return y >= 0.f ? y : 0.2f * y; }
__device__ __forceinline__ bf16x8 cvt8(const float* p){
  float4 a = *(const float4*)p;
  float4 b = *(const float4*)(p + 4);
  bf16x8 r;
  r[0] = (short)f2bf(a.x); r[1] = (short)f2bf(a.y); r[2] = (short)f2bf(a.z); r[3] = (short)f2bf(a.w);
  r[4] = (short)f2bf(b.x); r[5] = (short)f2bf(b.y); r[6] = (short)f2bf(b.z); r[7] = (short)f2bf(b.w);
  return r;
}

// ---------------- K1: C1 = lrelu(BN(x . w1)) only, pure streaming ----------------
__global__ __launch_bounds__(256) void k1_c1(
    const float* __restrict__ x, const float* __restrict__ w1,
    const float* __restrict__ pb1, const float* __restrict__ pg1,
    const float* __restrict__ pbe1, const float* __restrict__ pm1,
    const float* __restrict__ pv1,
    float* __restrict__ C1)
{
  const int blk = blockIdx.x;
  const int b = blk >> 6;
  const int n0 = (blk & 63) << 10;
  const int t = threadIdx.x;
  __shared__ float w1s[64];
  if (t < 64) w1s[t] = w1[t];
  __syncthreads();
  const float* xb = x + ((size_t)b << 22);
  const int n = n0 + (t << 2);
  float4 d = {0.f, 0.f, 0.f, 0.f};
  #pragma unroll 16
  for (int c = 0; c < 64; c++){
    const float4 xv = *(const float4*)(xb + ((size_t)c << 16) + n);
    const float wv = w1s[c];
    d.x = fmaf(xv.x, wv, d.x); d.y = fmaf(xv.y, wv, d.y);
    d.z = fmaf(xv.z, wv, d.z); d.w = fmaf(xv.w, wv, d.w);
  }
  const float s1 = pg1[0] * rsqrtf(pv1[0] + EPS);
  const float t1 = (pb1[0] - pm1[0]) * s1 + pbe1[0];
  float4 o;
  o.x = lrelu(d.x * s1 + t1); o.y = lrelu(d.y * s1 + t1);
  o.z = lrelu(d.z * s1 + t1); o.w = lrelu(d.w * s1 + t1);
  *(float4*)(C1 + (b << 16) + n) = o;
}

// ---------------- K2a: Gram partials, K-split 4 -> P[kh][which*8+b] in d_out[0,16MB) ----------------
// grid 1024: bx = b(3b) | which(1b) | tile(4b) | kh(2b); 64x64 tile, K=64 per block.
__global__ __launch_bounds__(256) void k2_gram(const float* __restrict__ C1, float* __restrict__ P)
{
  const int bx = blockIdx.x;
  const int kh = bx & 3;
  const int tile = (bx >> 2) & 15;
  const int which = (bx >> 6) & 1;
  const int b = bx >> 7;
  const int i0 = (tile >> 2) << 6, j0 = (tile & 3) << 6;
  const float* Cb = C1 + (b << 16);
  __shared__ float Al[32][68];
  __shared__ float Bl[32][68];
  const int t = threadIdx.x;
  const int tx = t & 15, ty = t >> 4;
  float acc[4][4];
  #pragma unroll
  for (int i = 0; i < 4; i++)
    #pragma unroll
    for (int j = 0; j < 4; j++) acc[i][j] = 0.f;

  for (int kc = 0; kc < 2; kc++){
    const int k0 = (kh << 6) + (kc << 5);
    __syncthreads();
    if (which == 0){
      const int i = t & 63, kq = t >> 6;
      const float* pa = Cb + (i0 + i)*256 + k0 + kq*8;
      const float* pb = Cb + (j0 + i)*256 + k0 + kq*8;
      #pragma unroll
      for (int u = 0; u < 8; u++){ Al[kq*8+u][i] = pa[u]; Bl[kq*8+u][i] = pb[u]; }
    } else {
      const int k = t >> 3, i8 = (t & 7) << 3;
      const float* pa = Cb + (k0 + k)*256 + i0 + i8;
      const float* pb = Cb + (k0 + k)*256 + j0 + i8;
      *(float4*)&Al[k][i8]   = *(const float4*)pa;
      *(float4*)&Al[k][i8+4] = *(const float4*)(pa+4);
      *(float4*)&Bl[k][i8]   = *(const float4*)pb;
      *(float4*)&Bl[k][i8+4] = *(const float4*)(pb+4);
    }
    __syncthreads();
    #pragma unroll 4
    for (int k = 0; k < 32; k++){
      float4 a4 = *(const float4*)&Al[k][ty << 2];
      float4 b4 = *(const float4*)&Bl[k][tx << 2];
      float av[4] = {a4.x, a4.y, a4.z, a4.w};
      float bw[4] = {b4.x, b4.y, b4.z, b4.w};
      #pragma unroll
      for (int ii = 0; ii < 4; ii++)
        #pragma unroll
        for (int jj = 0; jj < 4; jj++)
          acc[ii][jj] = fmaf(av[ii], bw[jj], acc[ii][jj]);
    }
  }
  float* Go = P + ((size_t)((kh << 4) + which*8 + b) << 16);
  #pragma unroll
  for (int r = 0; r < 4; r++){
    float4 o4 = {acc[r][0], acc[r][1], acc[r][2], acc[r][3]};
    *(float4*)&Go[(i0 + (ty<<2) + r)*256 + j0 + (tx<<2)] = o4;
  }
}

// ---------------- K2b: sum 4 partials -> row softmax -> S1,S2 (fp32) + permuted Ssum (bf16) ----------------
__global__ __launch_bounds__(256) void k2_softmax(const float* __restrict__ P,
    float* __restrict__ S1o, float* __restrict__ S2o,
    unsigned short* __restrict__ Ssum2)
{
  const int bx = blockIdx.x;
  const int b = bx >> 8, i = bx & 255;
  const int j = threadIdx.x;
  float v1 = 0.f, v2 = 0.f;
  #pragma unroll
  for (int kh = 0; kh < 4; kh++){
    v1 += P[((size_t)((kh << 4) + b) << 16) + i*256 + j];
    v2 += P[((size_t)((kh << 4) + 8 + b) << 16) + i*256 + j];
  }
  __shared__ float sm[4], sm2[4], ss[4], ss2[4];
  float a1 = v1, a2 = v2;
  #pragma unroll
  for (int off = 32; off > 0; off >>= 1){
    a1 = fmaxf(a1, __shfl_xor(a1, off));
    a2 = fmaxf(a2, __shfl_xor(a2, off));
  }
  const int wv = j >> 6;
  if ((j & 63) == 0){ sm[wv] = a1; sm2[wv] = a2; }
  __syncthreads();
  const float m1v = fmaxf(fmaxf(sm[0], sm[1]), fmaxf(sm[2], sm[3]));
  const float m2v = fmaxf(fmaxf(sm2[0], sm2[1]), fmaxf(sm2[2], sm2[3]));
  float e1 = __expf(v1 - m1v), e2 = __expf(v2 - m2v);
  float s1 = e1, s2 = e2;
  #pragma unroll
  for (int off = 32; off > 0; off >>= 1){
    s1 += __shfl_xor(s1, off);
    s2 += __shfl_xor(s2, off);
  }
  if ((j & 63) == 0){ ss[wv] = s1; ss2[wv] = s2; }
  __syncthreads();
  const float d1 = ss[0]+ss[1]+ss[2]+ss[3];
  const float d2 = ss2[0]+ss2[1]+ss2[2]+ss2[3];
  const float S1v = e1 / d1, S2v = e2 / d2;
  S1o[((size_t)b << 16) + i*256 + j] = S1v;
  S2o[((size_t)b << 16) + i*256 + j] = S2v;
  const int ip = ((i & 3) << 6) | (i >> 2);
  const int kp = ((j & 3) << 6) | (j >> 2);
  Ssum2[((size_t)b << 16) + ip*256 + kp] = f2bf(S1v + S2v);
}

// ---------------- K3: stage x -> C2 (MFMA, in-LDS) -> T' = Ssum2 @ R -> convO -> out ----------------
// grid 2048 (b*256 + jtile64), block 512 = 8 waves: wave wv = (quarter qo = wv>>1,
// col-half jh = (wv&1)*32), 32 positions each. Wave-own XL rows 32wv..32wv+31 in every
// phase. Single LDS buffer XL (36KB); 3 barriers. fp32 C2 residual in registers
// (MFMA1 D-layout == epilogue layout, lane-exact). launch_bounds(512,3): 168-reg
// budget (no spills), 3 blocks/CU = 24 waves/CU.
__global__ __launch_bounds__(512, 3) void k3_main(
    const float* __restrict__ x,
    const float* __restrict__ wA, const float* __restrict__ pbA,
    const float* __restrict__ pgA, const float* __restrict__ pbeA,
    const float* __restrict__ pmA, const float* __restrict__ pvA,
    const unsigned short* __restrict__ Ssum2,
    const float* __restrict__ wO, const float* __restrict__ pbO,
    const float* __restrict__ pgO, const float* __restrict__ pbeO,
    const float* __restrict__ pmO, const float* __restrict__ pvO,
    float* __restrict__ out)
{
  __shared__ unsigned short XL[256][72];   // bf16 [s = 32*wv + rl][c], +8 pad
  __shared__ float sAl[64], tAl[64], sOl[64], tOl[64];
  const int blk = blockIdx.x;
  const int b  = blk >> 8;
  const int j0 = (blk & 255) << 6;
  const int t = threadIdx.x;
  const int lane = t & 63, wv = t >> 6;    // wv 0..7
  const int m = lane & 15, ql = lane >> 4;
  const int qo = wv >> 1;                  // quarter (output band)
  const int jh = (wv & 1) << 5;            // col-half offset 0/32

  if (t < 64){
    const float sA = pgA[t] * rsqrtf(pvA[t] + EPS);
    sAl[t] = sA; tAl[t] = (pbA[t] - pmA[t]) * sA + pbeA[t];
    const float sO = pgO[t] * rsqrtf(pvO[t] + EPS);
    sOl[t] = sO; tOl[t] = (pbO[t] - pmO[t]) * sO + pbeO[t];
  }

  // ---- stage x strip (wave-own rows 32wv..32wv+31): lane = channel, 8 x dwordx4 ----
  // positions n = (qo<<14) + j0 + jh + rl, rl = 0..31
  {
    const float* xs = x + ((size_t)b << 22) + ((size_t)lane << 16) + (qo << 14) + j0 + jh;
    #pragma unroll
    for (int i = 0; i < 8; i++){
      const float4 xv = *(const float4*)(xs + 4*i);
      const int s = 32*wv + 4*i;
      XL[s+0][lane] = f2bf(xv.x);
      XL[s+1][lane] = f2bf(xv.y);
      XL[s+2][lane] = f2bf(xv.z);
      XL[s+3][lane] = f2bf(xv.w);
    }
  }
  __syncthreads();   // publishes BN consts (x rows are wave-own anyway)

  float sAv[4], tAv[4];
  #pragma unroll
  for (int ot = 0; ot < 4; ot++){ sAv[ot] = sAl[16*ot + m]; tAv[ot] = tAl[16*ot + m]; }

  // wA B-frags: wA[o][c] fp32 -> bf16, lane col = o-local (m), 8 consecutive c
  bf16x8 wfrA[4][2];
  #pragma unroll
  for (int ot = 0; ot < 4; ot++)
    #pragma unroll
    for (int ks = 0; ks < 2; ks++)
      wfrA[ot][ks] = cvt8(wA + (16*ot + m)*64 + ks*32 + ql*8);

  const f32x4 vzero = {0.f, 0.f, 0.f, 0.f};
  f32x4 c2r[2][4];   // [nt][ot] — fp32 C2 residual, held to the epilogue (32 regs)
  #pragma unroll
  for (int i = 0; i < 2; i++)
    #pragma unroll
    for (int j = 0; j < 4; j++) c2r[i][j] = vzero;

  // MFMA1: A-frags from wave-own XL rows (ds_read_b128)
  #pragma unroll
  for (int ks = 0; ks < 2; ks++)
    #pragma unroll
    for (int nt = 0; nt < 2; nt++){
      const bf16x8 af = *(const bf16x8*)&XL[32*wv + 16*nt + m][ks*32 + ql*8];
      #pragma unroll
      for (int ot = 0; ot < 4; ot++)
        c2r[nt][ot] = __builtin_amdgcn_mfma_f32_16x16x32_bf16(af, wfrA[ot][ks], c2r[nt][ot], 0, 0, 0);
    }

  // BN + LReLU (fp32 residual) + bf16 C2 into wave-own XL rows (overwrites x strip;
  // ordered by the MFMA data dependency on the fragment reads of the same rows).
  #pragma unroll
  for (int nt = 0; nt < 2; nt++)
    #pragma unroll
    for (int ot = 0; ot < 4; ot++){
      #pragma unroll
      for (int r = 0; r < 4; r++){
        const float v = lrelu(c2r[nt][ot][r] * sAv[ot] + tAv[ot]);
        c2r[nt][ot][r] = v;
        XL[32*wv + 16*nt + 4*ql + r][16*ot + m] = f2bf(v);
      }
    }
  __syncthreads();   // all C2 rows visible to all waves

  // GEMM1: T'[i'][col] = sum_k^ Ssum2[i'][k^] * C2[k^&63][(k^>>6)*16384 + col]
  // wave (qo, jh): i' rows 64qo..64qo+63; cols j0+jh+0..31.
  // B rows: XL[(q_k<<6) + jh + jl] (written by wave 2*q_k + (wv&1)) — cross-wave, barrier'd.
  const unsigned short* Sb = Ssum2 + ((size_t)b << 16);
  f32x4 accT[4][2];   // [it][jt] (32 regs)
  #pragma unroll
  for (int i = 0; i < 4; i++)
    #pragma unroll
    for (int j = 0; j < 2; j++) accT[i][j] = vzero;

  #pragma unroll
  for (int ks = 0; ks < 8; ks++){
    const int kk = ks*32 + ql*8;
    const int rk = kk >> 6;
    const int c0 = kk & 63;
    bf16x8 af[4], bv[2];
    #pragma unroll
    for (int it = 0; it < 4; it++)
      af[it] = *(const bf16x8*)(Sb + (64*qo + 16*it + m)*256 + kk);
    #pragma unroll
    for (int jt = 0; jt < 2; jt++)
      bv[jt] = *(const bf16x8*)&XL[(rk << 6) + jh + 16*jt + m][c0];
    #pragma unroll
    for (int it = 0; it < 4; it++)
      #pragma unroll
      for (int jt = 0; jt < 2; jt++)
        accT[it][jt] = __builtin_amdgcn_mfma_f32_16x16x32_bf16(af[it], bv[jt], accT[it][jt], 0, 0, 0);
  }
  __syncthreads();   // all waves done reading C2 before T' overwrites XL

  // T' -> wave-own XL rows [32wv + jl][c' = i'local]; GEMM2 (same wave) reads back.
  #pragma unroll
  for (int it = 0; it < 4; it++)
    #pragma unroll
    for (int jt = 0; jt < 2; jt++){
      uint2 pk;
      pk.x = (unsigned)f2bf(accT[it][jt][0]) | ((unsigned)f2bf(accT[it][jt][1]) << 16);
      pk.y = (unsigned)f2bf(accT[it][jt][2]) | ((unsigned)f2bf(accT[it][jt][3]) << 16);
      *(uint2*)&XL[32*wv + 16*jt + m][16*it + 4*ql] = pk;
    }

  // GEMM2: out_pre[s][cout] = sum_c' T[s][c'] * wO[cout][c']
  bf16x8 wfrO[4][2];
  #pragma unroll
  for (int ct = 0; ct < 4; ct++)
    #pragma unroll
    for (int k2 = 0; k2 < 2; k2++)
      wfrO[ct][k2] = cvt8(wO + (16*ct + m)*64 + k2*32 + ql*8);

  f32x4 acc2[2][4];
  #pragma unroll
  for (int i = 0; i < 2; i++)
    #pragma unroll
    for (int j = 0; j < 4; j++) acc2[i][j] = vzero;

  #pragma unroll
  for (int k2 = 0; k2 < 2; k2++)
    #pragma unroll
    for (int stl = 0; stl < 2; stl++){
      const bf16x8 afT = *(const bf16x8*)&XL[32*wv + 16*stl + m][k2*32 + ql*8];
      #pragma unroll
      for (int ct = 0; ct < 4; ct++)
        acc2[stl][ct] = __builtin_amdgcn_mfma_f32_16x16x32_bf16(afT, wfrO[ct][k2], acc2[stl][ct], 0, 0, 0);
    }

  float sOv[4], tOv[4];
  #pragma unroll
  for (int ct = 0; ct < 4; ct++){ sOv[ct] = sOl[16*ct + m]; tOv[ct] = tOl[16*ct + m]; }

  // epilogue: out = C2 (regs) + lrelu(BN_O(acc2)); block covers 64 consecutive floats
  // per cout row (256B granule), coalesced float4 stores.
  const size_t outB = ((size_t)b << 22);
  #pragma unroll
  for (int stl = 0; stl < 2; stl++)
    #pragma unroll
    for (int ct = 0; ct < 4; ct++){
      const int cout = 16*ct + m;
      const int ng0 = (qo << 14) + j0 + jh + 16*stl + 4*ql;
      float* po = out + outB + ((size_t)cout << 16) + ng0;
      float4 pk;
      pk.x = c2r[stl][ct][0] + lrelu(acc2[stl][ct][0] * sOv[ct] + tOv[ct]);
      pk.y = c2r[stl][ct][1] + lrelu(acc2[stl][ct][1] * sOv[ct] + tOv[ct]);
      pk.z = c2r[stl][ct][2] + lrelu(acc2[stl][ct][2] * sOv[ct] + tOv[ct]);
      pk.w = c2r[stl][ct][3] + lrelu(acc2[stl][ct][3] * sOv[ct] + tOv[ct]);
      *(float4*)po = pk;
    }
}

extern "C" void kernel_launch(void* const* d_in, const int* in_sizes, int n_in,
                              void* d_out, int out_size, void* d_ws, size_t ws_size,
                              hipStream_t stream) {
  const float* x   = (const float*)d_in[0];
  const float* w1  = (const float*)d_in[1];
  const float* b1  = (const float*)d_in[2];
  const float* g1  = (const float*)d_in[3];
  const float* be1 = (const float*)d_in[4];
  const float* m1  = (const float*)d_in[5];
  const float* v1  = (const float*)d_in[6];
  const float* wA  = (const float*)d_in[7];
  const float* bA  = (const float*)d_in[8];
  const float* gA  = (const float*)d_in[9];
  const float* beA = (const float*)d_in[10];
  const float* mA  = (const float*)d_in[11];
  const float* vA  = (const float*)d_in[12];
  const float* wO  = (const float*)d_in[13];
  const float* bO  = (const float*)d_in[14];
  const float* gO  = (const float*)d_in[15];
  const float* beO = (const float*)d_in[16];
  const float* mO  = (const float*)d_in[17];
  const float* vO  = (const float*)d_in[18];

  float* out = (float*)d_out;

  // ws layout (bytes): C1 fp32 [0,2M) | Ssum2 bf16 [6M,7M)
  // Gram partials P (16MB) live in d_out[0,16MB) — free until k3 overwrites out.
  char* ws = (char*)d_ws;
  float* C1             = (float*)(ws);
  unsigned short* Ssum2 = (unsigned short*)(ws + (size_t)(6u << 20));

  k1_c1<<<dim3(512), dim3(256), 0, stream>>>(x, w1, b1, g1, be1, m1, v1, C1);
  k2_gram<<<dim3(1024), dim3(256), 0, stream>>>(C1, out);
  k2_softmax<<<dim3(2048), dim3(256), 0, stream>>>(out, out + 33554432u, out + 34078720u, Ssum2);
  k3_main<<<dim3(2048), dim3(512), 0, stream>>>(x, wA, bA, gA, beA, mA, vA, Ssum2,
                                                wO, bO, gO, beO, mO, vO, out);
}

// Round 5
// 416.368 us; speedup vs baseline: 1.0748x; 1.0406x over previous
//
#include <hip/hip_runtime.h>

// SOAM fused pipeline v6, MI355X gfx950.
// Occupancy ledger across rounds: v3 (4-wave blk, ~256 total regs) -> 2 waves/SIMD, 108us.
// v4 ((256,4) forced 128-reg budget) -> spills (+137MB HBM), 172us. v5 (same shape, ~140
// regs, 512-thr blk) -> block quantization: 3 waves/SIMD available but 8-wave blocks need
// 2/SIMD each => 1 block/CU resident, 23% occ, 178us. v6 = v4's spill-free ~140-reg shape
// (j-tile 32, c2r[2][4]/accT[4][2]/acc2[2][4]) in 256-thread blocks at __launch_bounds__
// (256,3) (170-reg budget, proven sufficient by v5's clean compile): 3 blocks/CU = 12
// waves/CU = 37.5% residency, v3-clean HBM traffic, no spills.
// k1 (C1-only), k2a (K-split-4 Gram partials into d_out[0,16MB)), k2b (sum+softmax) kept.
// B=8, C=64, H=W=256. Identity: R1==R2 => R3+R4 = (S1+S2)@R. Permutations
// i'=(i&3)*64+(i>>2), k^=(k&3)*64+(k>>2) applied to Ssum when writing it.
// ws: C1 fp32 [0,2M) | Ssum2 bf16 [6M,7M).

#define EPS 1e-5f

typedef __attribute__((ext_vector_type(8))) short bf16x8;
typedef __attribute__((ext_vector_type(4))) float f32x4;

__device__ __forceinline__ unsigned short f2bf(float f){
  union { float f; unsigned int u; } a; a.f = f;
  return (unsigned short)((a.u + 0x7fffu + ((a.u >> 16) & 1u)) >> 16);
}
__device__ __forceinline__ float lrelu(float y){ return y >= 0.f ? y : 0.2f * y; }
__device__ __forceinline__ bf16x8 cvt8(const float* p){
  float4 a = *(const float4*)p;
  float4 b = *(const float4*)(p + 4);
  bf16x8 r;
  r[0] = (short)f2bf(a.x); r[1] = (short)f2bf(a.y); r[2] = (short)f2bf(a.z); r[3] = (short)f2bf(a.w);
  r[4] = (short)f2bf(b.x); r[5] = (short)f2bf(b.y); r[6] = (short)f2bf(b.z); r[7] = (short)f2bf(b.w);
  return r;
}

// ---------------- K1: C1 = lrelu(BN(x . w1)) only, pure streaming ----------------
__global__ __launch_bounds__(256) void k1_c1(
    const float* __restrict__ x, const float* __restrict__ w1,
    const float* __restrict__ pb1, const float* __restrict__ pg1,
    const float* __restrict__ pbe1, const float* __restrict__ pm1,
    const float* __restrict__ pv1,
    float* __restrict__ C1)
{
  const int blk = blockIdx.x;
  const int b = blk >> 6;
  const int n0 = (blk & 63) << 10;
  const int t = threadIdx.x;
  __shared__ float w1s[64];
  if (t < 64) w1s[t] = w1[t];
  __syncthreads();
  const float* xb = x + ((size_t)b << 22);
  const int n = n0 + (t << 2);
  float4 d = {0.f, 0.f, 0.f, 0.f};
  #pragma unroll 16
  for (int c = 0; c < 64; c++){
    const float4 xv = *(const float4*)(xb + ((size_t)c << 16) + n);
    const float wv = w1s[c];
    d.x = fmaf(xv.x, wv, d.x); d.y = fmaf(xv.y, wv, d.y);
    d.z = fmaf(xv.z, wv, d.z); d.w = fmaf(xv.w, wv, d.w);
  }
  const float s1 = pg1[0] * rsqrtf(pv1[0] + EPS);
  const float t1 = (pb1[0] - pm1[0]) * s1 + pbe1[0];
  float4 o;
  o.x = lrelu(d.x * s1 + t1); o.y = lrelu(d.y * s1 + t1);
  o.z = lrelu(d.z * s1 + t1); o.w = lrelu(d.w * s1 + t1);
  *(float4*)(C1 + (b << 16) + n) = o;
}

// ---------------- K2a: Gram partials, K-split 4 -> P[kh][which*8+b] in d_out[0,16MB) ----------------
// grid 1024: bx = b(3b) | which(1b) | tile(4b) | kh(2b); 64x64 tile, K=64 per block.
__global__ __launch_bounds__(256) void k2_gram(const float* __restrict__ C1, float* __restrict__ P)
{
  const int bx = blockIdx.x;
  const int kh = bx & 3;
  const int tile = (bx >> 2) & 15;
  const int which = (bx >> 6) & 1;
  const int b = bx >> 7;
  const int i0 = (tile >> 2) << 6, j0 = (tile & 3) << 6;
  const float* Cb = C1 + (b << 16);
  __shared__ float Al[32][68];
  __shared__ float Bl[32][68];
  const int t = threadIdx.x;
  const int tx = t & 15, ty = t >> 4;
  float acc[4][4];
  #pragma unroll
  for (int i = 0; i < 4; i++)
    #pragma unroll
    for (int j = 0; j < 4; j++) acc[i][j] = 0.f;

  for (int kc = 0; kc < 2; kc++){
    const int k0 = (kh << 6) + (kc << 5);
    __syncthreads();
    if (which == 0){
      const int i = t & 63, kq = t >> 6;
      const float* pa = Cb + (i0 + i)*256 + k0 + kq*8;
      const float* pb = Cb + (j0 + i)*256 + k0 + kq*8;
      #pragma unroll
      for (int u = 0; u < 8; u++){ Al[kq*8+u][i] = pa[u]; Bl[kq*8+u][i] = pb[u]; }
    } else {
      const int k = t >> 3, i8 = (t & 7) << 3;
      const float* pa = Cb + (k0 + k)*256 + i0 + i8;
      const float* pb = Cb + (k0 + k)*256 + j0 + i8;
      *(float4*)&Al[k][i8]   = *(const float4*)pa;
      *(float4*)&Al[k][i8+4] = *(const float4*)(pa+4);
      *(float4*)&Bl[k][i8]   = *(const float4*)pb;
      *(float4*)&Bl[k][i8+4] = *(const float4*)(pb+4);
    }
    __syncthreads();
    #pragma unroll 4
    for (int k = 0; k < 32; k++){
      float4 a4 = *(const float4*)&Al[k][ty << 2];
      float4 b4 = *(const float4*)&Bl[k][tx << 2];
      float av[4] = {a4.x, a4.y, a4.z, a4.w};
      float bw[4] = {b4.x, b4.y, b4.z, b4.w};
      #pragma unroll
      for (int ii = 0; ii < 4; ii++)
        #pragma unroll
        for (int jj = 0; jj < 4; jj++)
          acc[ii][jj] = fmaf(av[ii], bw[jj], acc[ii][jj]);
    }
  }
  float* Go = P + ((size_t)((kh << 4) + which*8 + b) << 16);
  #pragma unroll
  for (int r = 0; r < 4; r++){
    float4 o4 = {acc[r][0], acc[r][1], acc[r][2], acc[r][3]};
    *(float4*)&Go[(i0 + (ty<<2) + r)*256 + j0 + (tx<<2)] = o4;
  }
}

// ---------------- K2b: sum 4 partials -> row softmax -> S1,S2 (fp32) + permuted Ssum (bf16) ----------------
__global__ __launch_bounds__(256) void k2_softmax(const float* __restrict__ P,
    float* __restrict__ S1o, float* __restrict__ S2o,
    unsigned short* __restrict__ Ssum2)
{
  const int bx = blockIdx.x;
  const int b = bx >> 8, i = bx & 255;
  const int j = threadIdx.x;
  float v1 = 0.f, v2 = 0.f;
  #pragma unroll
  for (int kh = 0; kh < 4; kh++){
    v1 += P[((size_t)((kh << 4) + b) << 16) + i*256 + j];
    v2 += P[((size_t)((kh << 4) + 8 + b) << 16) + i*256 + j];
  }
  __shared__ float sm[4], sm2[4], ss[4], ss2[4];
  float a1 = v1, a2 = v2;
  #pragma unroll
  for (int off = 32; off > 0; off >>= 1){
    a1 = fmaxf(a1, __shfl_xor(a1, off));
    a2 = fmaxf(a2, __shfl_xor(a2, off));
  }
  const int wv = j >> 6;
  if ((j & 63) == 0){ sm[wv] = a1; sm2[wv] = a2; }
  __syncthreads();
  const float m1v = fmaxf(fmaxf(sm[0], sm[1]), fmaxf(sm[2], sm[3]));
  const float m2v = fmaxf(fmaxf(sm2[0], sm2[1]), fmaxf(sm2[2], sm2[3]));
  float e1 = __expf(v1 - m1v), e2 = __expf(v2 - m2v);
  float s1 = e1, s2 = e2;
  #pragma unroll
  for (int off = 32; off > 0; off >>= 1){
    s1 += __shfl_xor(s1, off);
    s2 += __shfl_xor(s2, off);
  }
  if ((j & 63) == 0){ ss[wv] = s1; ss2[wv] = s2; }
  __syncthreads();
  const float d1 = ss[0]+ss[1]+ss[2]+ss[3];
  const float d2 = ss2[0]+ss2[1]+ss2[2]+ss2[3];
  const float S1v = e1 / d1, S2v = e2 / d2;
  S1o[((size_t)b << 16) + i*256 + j] = S1v;
  S2o[((size_t)b << 16) + i*256 + j] = S2v;
  const int ip = ((i & 3) << 6) | (i >> 2);
  const int kp = ((j & 3) << 6) | (j >> 2);
  Ssum2[((size_t)b << 16) + ip*256 + kp] = f2bf(S1v + S2v);
}

// ---------------- K3: stage x -> C2 (MFMA, in-LDS) -> T' = Ssum2 @ R -> convO -> out ----------------
// grid 4096 (b*512 + jtile32), block 256 = 4 waves, wave = band (32 j-positions each).
// Single LDS buffer XL (18KB): x (bf16 [s][c]) -> C2 (wave-own rows) -> barrier ->
// GEMM1 operand -> barrier -> T' (wave-own rows) -> GEMM2 operand.
// fp32 C2 residual in registers (MFMA1 D-layout == epilogue layout, lane-exact).
// __launch_bounds__(256,3): 170-reg budget (shape needs ~140, spill-free per v5's
// compile) -> 3 blocks/CU = 12 waves/CU. Do NOT use (256,4): 128 budget spills (v4).
__global__ __launch_bounds__(256, 3) void k3_main(
    const float* __restrict__ x,
    const float* __restrict__ wA, const float* __restrict__ pbA,
    const float* __restrict__ pgA, const float* __restrict__ pbeA,
    const float* __restrict__ pmA, const float* __restrict__ pvA,
    const unsigned short* __restrict__ Ssum2,
    const float* __restrict__ wO, const float* __restrict__ pbO,
    const float* __restrict__ pgO, const float* __restrict__ pbeO,
    const float* __restrict__ pmO, const float* __restrict__ pvO,
    float* __restrict__ out)
{
  __shared__ unsigned short XL[128][72];   // bf16 [s = band*32 + jl][c], +8 pad
  __shared__ float sAl[64], tAl[64], sOl[64], tOl[64];
  const int blk = blockIdx.x;
  const int b  = blk >> 9;
  const int j0 = (blk & 511) << 5;
  const int t = threadIdx.x;
  const int lane = t & 63, wv = t >> 6;
  const int m = lane & 15, q = lane >> 4;

  if (t < 64){
    const float sA = pgA[t] * rsqrtf(pvA[t] + EPS);
    sAl[t] = sA; tAl[t] = (pbA[t] - pmA[t]) * sA + pbeA[t];
    const float sO = pgO[t] * rsqrtf(pvO[t] + EPS);
    sOl[t] = sO; tOl[t] = (pbO[t] - pmO[t]) * sO + pbeO[t];
  }

  // ---- stage x strip (wave-own rows): lane = channel, 8 x dwordx4 per thread ----
  // wave wv = band wv: global positions (wv<<14) + j0 .. +31; rows 32wv..32wv+31.
  {
    const float* xs = x + ((size_t)b << 22) + ((size_t)lane << 16) + (wv << 14) + j0;
    #pragma unroll
    for (int i = 0; i < 8; i++){
      const float4 xv = *(const float4*)(xs + 4*i);
      const int s = 32*wv + 4*i;
      XL[s+0][lane] = f2bf(xv.x);
      XL[s+1][lane] = f2bf(xv.y);
      XL[s+2][lane] = f2bf(xv.z);
      XL[s+3][lane] = f2bf(xv.w);
    }
  }
  __syncthreads();   // publishes sAl/tAl/sOl/tOl (x rows are wave-own anyway)

  float sAv[4], tAv[4];
  #pragma unroll
  for (int ot = 0; ot < 4; ot++){ sAv[ot] = sAl[16*ot + m]; tAv[ot] = tAl[16*ot + m]; }

  // wA B-frags: wA[o][c] fp32 -> bf16, lane col = o-local (m), 8 consecutive c
  bf16x8 wfrA[4][2];
  #pragma unroll
  for (int ot = 0; ot < 4; ot++)
    #pragma unroll
    for (int ks = 0; ks < 2; ks++)
      wfrA[ot][ks] = cvt8(wA + (16*ot + m)*64 + ks*32 + q*8);

  const f32x4 vzero = {0.f, 0.f, 0.f, 0.f};
  f32x4 c2r[2][4];   // [nt][ot] — fp32 C2 residual, held to the epilogue (32 regs)
  #pragma unroll
  for (int i = 0; i < 2; i++)
    #pragma unroll
    for (int j = 0; j < 4; j++) c2r[i][j] = vzero;

  // MFMA1: A-frags straight from XL (ds_read_b128); wave-own rows 32wv + 16nt + m
  #pragma unroll
  for (int ks = 0; ks < 2; ks++)
    #pragma unroll
    for (int nt = 0; nt < 2; nt++){
      const bf16x8 af = *(const bf16x8*)&XL[32*wv + 16*nt + m][ks*32 + q*8];
      #pragma unroll
      for (int ot = 0; ot < 4; ot++)
        c2r[nt][ot] = __builtin_amdgcn_mfma_f32_16x16x32_bf16(af, wfrA[ot][ks], c2r[nt][ot], 0, 0, 0);
    }

  // BN + LReLU (fp32 residual) + bf16 C2 into XL (overwrites x; wave-own rows,
  // ordered by the MFMA data dependency on the fragment reads of the same row group).
  #pragma unroll
  for (int nt = 0; nt < 2; nt++)
    #pragma unroll
    for (int ot = 0; ot < 4; ot++){
      #pragma unroll
      for (int r = 0; r < 4; r++){
        const float v = lrelu(c2r[nt][ot][r] * sAv[ot] + tAv[ot]);
        c2r[nt][ot][r] = v;
        XL[32*wv + 16*nt + 4*q + r][16*ot + m] = f2bf(v);
      }
    }
  __syncthreads();   // all C2 rows visible to all waves

  // GEMM1: T'[i'][j] = sum_k^ Ssum2[i'][k^] * XL[(k^>>6)*32 + jl][k^&63]
  // wave wv owns i' rows 64wv..64wv+63 (i' group == band), jl 0..31.
  const unsigned short* Sb = Ssum2 + ((size_t)b << 16);
  f32x4 accT[4][2];   // [it][jt] (32 regs)
  #pragma unroll
  for (int i = 0; i < 4; i++)
    #pragma unroll
    for (int j = 0; j < 2; j++) accT[i][j] = vzero;

  #pragma unroll
  for (int ks = 0; ks < 8; ks++){
    const int kk = ks*32 + q*8;
    const int rk = kk >> 6;
    const int c0 = kk & 63;
    bf16x8 af[4], bv[2];
    #pragma unroll
    for (int it = 0; it < 4; it++)
      af[it] = *(const bf16x8*)(Sb + (64*wv + 16*it + m)*256 + kk);
    #pragma unroll
    for (int jt = 0; jt < 2; jt++)
      bv[jt] = *(const bf16x8*)&XL[(rk << 5) + 16*jt + m][c0];
    #pragma unroll
    for (int it = 0; it < 4; it++)
      #pragma unroll
      for (int jt = 0; jt < 2; jt++)
        accT[it][jt] = __builtin_amdgcn_mfma_f32_16x16x32_bf16(af[it], bv[jt], accT[it][jt], 0, 0, 0);
  }
  __syncthreads();   // all waves done reading C2 before T' overwrites XL

  // T' -> XL wave-own rows [32wv + jl][c' = i'_local]; GEMM2 (same wave) reads back.
  #pragma unroll
  for (int it = 0; it < 4; it++)
    #pragma unroll
    for (int jt = 0; jt < 2; jt++){
      uint2 pk;
      pk.x = (unsigned)f2bf(accT[it][jt][0]) | ((unsigned)f2bf(accT[it][jt][1]) << 16);
      pk.y = (unsigned)f2bf(accT[it][jt][2]) | ((unsigned)f2bf(accT[it][jt][3]) << 16);
      *(uint2*)&XL[32*wv + 16*jt + m][16*it + 4*q] = pk;
    }

  // GEMM2: out_pre[s][cout] = sum_c' T[s][c'] * wO[cout][c']
  bf16x8 wfrO[4][2];
  #pragma unroll
  for (int ct = 0; ct < 4; ct++)
    #pragma unroll
    for (int k2 = 0; k2 < 2; k2++)
      wfrO[ct][k2] = cvt8(wO + (16*ct + m)*64 + k2*32 + q*8);

  f32x4 acc2[2][4];
  #pragma unroll
  for (int i = 0; i < 2; i++)
    #pragma unroll
    for (int j = 0; j < 4; j++) acc2[i][j] = vzero;

  #pragma unroll
  for (int k2 = 0; k2 < 2; k2++)
    #pragma unroll
    for (int stl = 0; stl < 2; stl++){
      const bf16x8 afT = *(const bf16x8*)&XL[32*wv + 16*stl + m][k2*32 + q*8];
      #pragma unroll
      for (int ct = 0; ct < 4; ct++)
        acc2[stl][ct] = __builtin_amdgcn_mfma_f32_16x16x32_bf16(afT, wfrO[ct][k2], acc2[stl][ct], 0, 0, 0);
    }

  float sOv[4], tOv[4];
  #pragma unroll
  for (int ct = 0; ct < 4; ct++){ sOv[ct] = sOl[16*ct + m]; tOv[ct] = tOl[16*ct + m]; }

  // epilogue: out = C2 (regs) + lrelu(BN_O(acc2)); pure coalesced float4 store
  const size_t outB = ((size_t)b << 22);
  #pragma unroll
  for (int stl = 0; stl < 2; stl++)
    #pragma unroll
    for (int ct = 0; ct < 4; ct++){
      const int cout = 16*ct + m;
      const int ng0 = (wv << 14) + j0 + 16*stl + 4*q;
      float* po = out + outB + ((size_t)cout << 16) + ng0;
      float4 pk;
      pk.x = c2r[stl][ct][0] + lrelu(acc2[stl][ct][0] * sOv[ct] + tOv[ct]);
      pk.y = c2r[stl][ct][1] + lrelu(acc2[stl][ct][1] * sOv[ct] + tOv[ct]);
      pk.z = c2r[stl][ct][2] + lrelu(acc2[stl][ct][2] * sOv[ct] + tOv[ct]);
      pk.w = c2r[stl][ct][3] + lrelu(acc2[stl][ct][3] * sOv[ct] + tOv[ct]);
      *(float4*)po = pk;
    }
}

extern "C" void kernel_launch(void* const* d_in, const int* in_sizes, int n_in,
                              void* d_out, int out_size, void* d_ws, size_t ws_size,
                              hipStream_t stream) {
  const float* x   = (const float*)d_in[0];
  const float* w1  = (const float*)d_in[1];
  const float* b1  = (const float*)d_in[2];
  const float* g1  = (const float*)d_in[3];
  const float* be1 = (const float*)d_in[4];
  const float* m1  = (const float*)d_in[5];
  const float* v1  = (const float*)d_in[6];
  const float* wA  = (const float*)d_in[7];
  const float* bA  = (const float*)d_in[8];
  const float* gA  = (const float*)d_in[9];
  const float* beA = (const float*)d_in[10];
  const float* mA  = (const float*)d_in[11];
  const float* vA  = (const float*)d_in[12];
  const float* wO  = (const float*)d_in[13];
  const float* bO  = (const float*)d_in[14];
  const float* gO  = (const float*)d_in[15];
  const float* beO = (const float*)d_in[16];
  const float* mO  = (const float*)d_in[17];
  const float* vO  = (const float*)d_in[18];

  float* out = (float*)d_out;

  // ws layout (bytes): C1 fp32 [0,2M) | Ssum2 bf16 [6M,7M)
  // Gram partials P (16MB) live in d_out[0,16MB) — free until k3 overwrites out.
  char* ws = (char*)d_ws;
  float* C1             = (float*)(ws);
  unsigned short* Ssum2 = (unsigned short*)(ws + (size_t)(6u << 20));

  k1_c1<<<dim3(512), dim3(256), 0, stream>>>(x, w1, b1, g1, be1, m1, v1, C1);
  k2_gram<<<dim3(1024), dim3(256), 0, stream>>>(C1, out);
  k2_softmax<<<dim3(2048), dim3(256), 0, stream>>>(out, out + 33554432u, out + 34078720u, Ssum2);
  k3_main<<<dim3(4096), dim3(256), 0, stream>>>(x, wA, bA, gA, beA, mA, vA, Ssum2,
                                                wO, bO, gO, beO, mO, vO, out);
}

// Round 7
// 401.189 us; speedup vs baseline: 1.1155x; 1.0378x over previous
//
#include <hip/hip_runtime.h>

// SOAM fused pipeline v8, MI355X gfx950.
// v7 post-mortem: FAILED correctness (absmax 0.45). Cause: k3's position partition was
// changed to 256 contiguous positions (nbase = n0 + 64wv) while GEMM1's row indexing
// XL[(rk<<6)+jl] assumes the STRIP mapping — block owns columns [j0,j0+64) and the four
// strips {rk*16384 + j0 + [0,64)} (one per image quarter); wave wv's outputs land at
// (wv<<14)+j0. v8 restores the strip mapping (j0 = (blk&255)<<6; x gather and epilogue
// at (wv<<14)+j0) and keeps v7's register-capping structure:
//   GEMM1 split into two it-passes (accT[2][4]; pass-A T' packed to bf16 in 16 regs),
//   GEMM2 split into two stl-halves. Peak live ~150 regs -> __launch_bounds__(256,3)
//   = 3 blocks/CU = 12 waves/CU (v2 was 2 blocks/CU at ~210 regs).
// Ledger: v2 104us (19.8% occ); v3 stage-x 108us (staging pure overhead - no reuse);
// v4 (256,4) spilled; v5 512-thr hit block quantization (1 blk/CU); v6 j-tile-32 162us
// (halved per-wave work -> latency collapse). v8 = v2 work shape + 1.5x residency.
// k1: float2/thread, grid 1024. k2a: K-split-4 Gram partials in d_out[0,16MB).
// B=8, C=64, H=W=256. Identity: R1==R2 => R3+R4 = (S1+S2)@R. Permutations
// i'=(i&3)*64+(i>>2), k^=(k&3)*64+(k>>2) applied to Ssum when writing it.
// ws: C1 fp32 [0,2M) | Ssum2 bf16 [6M,7M).

#define EPS 1e-5f

typedef __attribute__((ext_vector_type(8))) short bf16x8;
typedef __attribute__((ext_vector_type(4))) float f32x4;

__device__ __forceinline__ unsigned short f2bf(float f){
  union { float f; unsigned int u; } a; a.f = f;
  return (unsigned short)((a.u + 0x7fffu + ((a.u >> 16) & 1u)) >> 16);
}
__device__ __forceinline__ float lrelu(float y){ return y >= 0.f ? y : 0.2f * y; }
__device__ __forceinline__ bf16x8 cvt8(const float* p){
  float4 a = *(const float4*)p;
  float4 b = *(const float4*)(p + 4);
  bf16x8 r;
  r[0] = (short)f2bf(a.x); r[1] = (short)f2bf(a.y); r[2] = (short)f2bf(a.z); r[3] = (short)f2bf(a.w);
  r[4] = (short)f2bf(b.x); r[5] = (short)f2bf(b.y); r[6] = (short)f2bf(b.z); r[7] = (short)f2bf(b.w);
  return r;
}

// ---------------- K1: C1 = lrelu(BN(x . w1)), pure streaming, float2/thread ----------------
__global__ __launch_bounds__(256) void k1_c1(
    const float* __restrict__ x, const float* __restrict__ w1,
    const float* __restrict__ pb1, const float* __restrict__ pg1,
    const float* __restrict__ pbe1, const float* __restrict__ pm1,
    const float* __restrict__ pv1,
    float* __restrict__ C1)
{
  const int blk = blockIdx.x;
  const int b = blk >> 7;
  const int n0 = (blk & 127) << 9;
  const int t = threadIdx.x;
  __shared__ float w1s[64];
  if (t < 64) w1s[t] = w1[t];
  __syncthreads();
  const float* xb = x + ((size_t)b << 22);
  const int n = n0 + (t << 1);
  float2 d = {0.f, 0.f};
  #pragma unroll 16
  for (int c = 0; c < 64; c++){
    const float2 xv = *(const float2*)(xb + ((size_t)c << 16) + n);
    const float wv = w1s[c];
    d.x = fmaf(xv.x, wv, d.x); d.y = fmaf(xv.y, wv, d.y);
  }
  const float s1 = pg1[0] * rsqrtf(pv1[0] + EPS);
  const float t1 = (pb1[0] - pm1[0]) * s1 + pbe1[0];
  float2 o;
  o.x = lrelu(d.x * s1 + t1); o.y = lrelu(d.y * s1 + t1);
  *(float2*)(C1 + (b << 16) + n) = o;
}

// ---------------- K2a: Gram partials, K-split 4 -> P[kh][which*8+b] in d_out[0,16MB) ----------------
__global__ __launch_bounds__(256) void k2_gram(const float* __restrict__ C1, float* __restrict__ P)
{
  const int bx = blockIdx.x;
  const int kh = bx & 3;
  const int tile = (bx >> 2) & 15;
  const int which = (bx >> 6) & 1;
  const int b = bx >> 7;
  const int i0 = (tile >> 2) << 6, j0 = (tile & 3) << 6;
  const float* Cb = C1 + (b << 16);
  __shared__ float Al[32][68];
  __shared__ float Bl[32][68];
  const int t = threadIdx.x;
  const int tx = t & 15, ty = t >> 4;
  float acc[4][4];
  #pragma unroll
  for (int i = 0; i < 4; i++)
    #pragma unroll
    for (int j = 0; j < 4; j++) acc[i][j] = 0.f;

  for (int kc = 0; kc < 2; kc++){
    const int k0 = (kh << 6) + (kc << 5);
    __syncthreads();
    if (which == 0){
      const int i = t & 63, kq = t >> 6;
      const float* pa = Cb + (i0 + i)*256 + k0 + kq*8;
      const float* pb = Cb + (j0 + i)*256 + k0 + kq*8;
      #pragma unroll
      for (int u = 0; u < 8; u++){ Al[kq*8+u][i] = pa[u]; Bl[kq*8+u][i] = pb[u]; }
    } else {
      const int k = t >> 3, i8 = (t & 7) << 3;
      const float* pa = Cb + (k0 + k)*256 + i0 + i8;
      const float* pb = Cb + (k0 + k)*256 + j0 + i8;
      *(float4*)&Al[k][i8]   = *(const float4*)pa;
      *(float4*)&Al[k][i8+4] = *(const float4*)(pa+4);
      *(float4*)&Bl[k][i8]   = *(const float4*)pb;
      *(float4*)&Bl[k][i8+4] = *(const float4*)(pb+4);
    }
    __syncthreads();
    #pragma unroll 4
    for (int k = 0; k < 32; k++){
      float4 a4 = *(const float4*)&Al[k][ty << 2];
      float4 b4 = *(const float4*)&Bl[k][tx << 2];
      float av[4] = {a4.x, a4.y, a4.z, a4.w};
      float bw[4] = {b4.x, b4.y, b4.z, b4.w};
      #pragma unroll
      for (int ii = 0; ii < 4; ii++)
        #pragma unroll
        for (int jj = 0; jj < 4; jj++)
          acc[ii][jj] = fmaf(av[ii], bw[jj], acc[ii][jj]);
    }
  }
  float* Go = P + ((size_t)((kh << 4) + which*8 + b) << 16);
  #pragma unroll
  for (int r = 0; r < 4; r++){
    float4 o4 = {acc[r][0], acc[r][1], acc[r][2], acc[r][3]};
    *(float4*)&Go[(i0 + (ty<<2) + r)*256 + j0 + (tx<<2)] = o4;
  }
}

// ---------------- K2b: sum 4 partials -> row softmax -> S1,S2 (fp32) + permuted Ssum (bf16) ----------------
__global__ __launch_bounds__(256) void k2_softmax(const float* __restrict__ P,
    float* __restrict__ S1o, float* __restrict__ S2o,
    unsigned short* __restrict__ Ssum2)
{
  const int bx = blockIdx.x;
  const int b = bx >> 8, i = bx & 255;
  const int j = threadIdx.x;
  float v1 = 0.f, v2 = 0.f;
  #pragma unroll
  for (int kh = 0; kh < 4; kh++){
    v1 += P[((size_t)((kh << 4) + b) << 16) + i*256 + j];
    v2 += P[((size_t)((kh << 4) + 8 + b) << 16) + i*256 + j];
  }
  __shared__ float sm[4], sm2[4], ss[4], ss2[4];
  float a1 = v1, a2 = v2;
  #pragma unroll
  for (int off = 32; off > 0; off >>= 1){
    a1 = fmaxf(a1, __shfl_xor(a1, off));
    a2 = fmaxf(a2, __shfl_xor(a2, off));
  }
  const int wv = j >> 6;
  if ((j & 63) == 0){ sm[wv] = a1; sm2[wv] = a2; }
  __syncthreads();
  const float m1v = fmaxf(fmaxf(sm[0], sm[1]), fmaxf(sm[2], sm[3]));
  const float m2v = fmaxf(fmaxf(sm2[0], sm2[1]), fmaxf(sm2[2], sm2[3]));
  float e1 = __expf(v1 - m1v), e2 = __expf(v2 - m2v);
  float s1 = e1, s2 = e2;
  #pragma unroll
  for (int off = 32; off > 0; off >>= 1){
    s1 += __shfl_xor(s1, off);
    s2 += __shfl_xor(s2, off);
  }
  if ((j & 63) == 0){ ss[wv] = s1; ss2[wv] = s2; }
  __syncthreads();
  const float d1 = ss[0]+ss[1]+ss[2]+ss[3];
  const float d2 = ss2[0]+ss2[1]+ss2[2]+ss2[3];
  const float S1v = e1 / d1, S2v = e2 / d2;
  S1o[((size_t)b << 16) + i*256 + j] = S1v;
  S2o[((size_t)b << 16) + i*256 + j] = S2v;
  const int ip = ((i & 3) << 6) | (i >> 2);
  const int kp = ((j & 3) << 6) | (j >> 2);
  Ssum2[((size_t)b << 16) + ip*256 + kp] = f2bf(S1v + S2v);
}

// ---------------- K3: direct-gather C2 (MFMA) -> T' = Ssum2 @ R -> convO -> out ----------------
// grid 2048 (b*256 + coltile j0), block 256 = 4 waves. STRIP mapping: wave wv owns
// global positions (wv<<14) + j0 + [0,64) (one strip per image quarter); XL row
// s = 64wv + jl <-> position (wv<<14) + j0 + jl, so GEMM1's B-read XL[(rk<<6)+jl]
// fetches C2 at (rk<<14)+j0+jl as the identity requires.
// Two-pass GEMM1 (pass-A T' packed bf16 in regs across the barrier) + split GEMM2
// cap peak live at ~150 regs -> (256,3) = 3 blocks/CU.
__global__ __launch_bounds__(256, 3) void k3_main(
    const float* __restrict__ x,
    const float* __restrict__ wA, const float* __restrict__ pbA,
    const float* __restrict__ pgA, const float* __restrict__ pbeA,
    const float* __restrict__ pmA, const float* __restrict__ pvA,
    const unsigned short* __restrict__ Ssum2,
    const float* __restrict__ wO, const float* __restrict__ pbO,
    const float* __restrict__ pgO, const float* __restrict__ pbeO,
    const float* __restrict__ pmO, const float* __restrict__ pvO,
    float* __restrict__ out)
{
  __shared__ unsigned short XL[256][72];   // bf16 [s = 64*wv + jl][c], +8 pad
  __shared__ float sAl[64], tAl[64], sOl[64], tOl[64];
  const int blk = blockIdx.x;
  const int b  = blk >> 8;
  const int j0 = (blk & 255) << 6;         // column tile (strip offset)
  const int t = threadIdx.x;
  const int lane = t & 63, wv = t >> 6;
  const int m = lane & 15, q = lane >> 4;

  if (t < 64){
    const float sA = pgA[t] * rsqrtf(pvA[t] + EPS);
    sAl[t] = sA; tAl[t] = (pbA[t] - pmA[t]) * sA + pbeA[t];
    const float sO = pgO[t] * rsqrtf(pvO[t] + EPS);
    sOl[t] = sO; tOl[t] = (pbO[t] - pmO[t]) * sO + pbeO[t];
  }
  __syncthreads();

  float sAv[4], tAv[4];
  #pragma unroll
  for (int ot = 0; ot < 4; ot++){ sAv[ot] = sAl[16*ot + m]; tAv[ot] = tAl[16*ot + m]; }

  // wA B-frags: wA[o][c] fp32 -> bf16, lane col = o-local (m), 8 consecutive c
  bf16x8 wfrA[4][2];
  #pragma unroll
  for (int ot = 0; ot < 4; ot++)
    #pragma unroll
    for (int ks = 0; ks < 2; ks++)
      wfrA[ot][ks] = cvt8(wA + (16*ot + m)*64 + ks*32 + q*8);

  const f32x4 vzero = {0.f, 0.f, 0.f, 0.f};
  f32x4 c2r[4][4];   // [nt][ot] — fp32 C2 residual, held to the epilogue
  #pragma unroll
  for (int i = 0; i < 4; i++)
    #pragma unroll
    for (int j = 0; j < 4; j++) c2r[i][j] = vzero;

  // MFMA1 via direct gather (v2): wave wv's strip = (wv<<14) + j0 + [0,64)
  const float* xb = x + ((size_t)b << 22) + (wv << 14) + j0;
  #pragma unroll
  for (int ks = 0; ks < 2; ks++)
    #pragma unroll
    for (int nt = 0; nt < 4; nt++){
      bf16x8 af;
      #pragma unroll
      for (int u = 0; u < 8; u++){
        const int c = ks*32 + q*8 + u;
        af[u] = (short)f2bf(xb[((size_t)c << 16) + 16*nt + m]);
      }
      #pragma unroll
      for (int ot = 0; ot < 4; ot++)
        c2r[nt][ot] = __builtin_amdgcn_mfma_f32_16x16x32_bf16(af, wfrA[ot][ks], c2r[nt][ot], 0, 0, 0);
    }

  // BN + LReLU (fp32 residual) + bf16 C2 into XL (wave-own rows)
  #pragma unroll
  for (int nt = 0; nt < 4; nt++)
    #pragma unroll
    for (int ot = 0; ot < 4; ot++){
      #pragma unroll
      for (int r = 0; r < 4; r++){
        const float v = lrelu(c2r[nt][ot][r] * sAv[ot] + tAv[ot]);
        c2r[nt][ot][r] = v;
        XL[64*wv + 16*nt + 4*q + r][16*ot + m] = f2bf(v);
      }
    }
  __syncthreads();   // all C2 rows visible to all waves

  // GEMM1: T'[i'][jl] = sum_k^ Ssum2[i'][k^] * XL[(k^>>6)*64 + jl][k^&63]
  // wave wv owns i' rows 64wv..64wv+63, jl 0..63. Two it-passes to cap live regs.
  const unsigned short* Sb = Ssum2 + ((size_t)b << 16);

  // ---- pass A: it = 0,1 -> tp0 (packed bf16, 16 regs) ----
  uint2 tp0[2][4];
  {
    f32x4 aT[2][4];
    #pragma unroll
    for (int i = 0; i < 2; i++)
      #pragma unroll
      for (int j = 0; j < 4; j++) aT[i][j] = vzero;
    #pragma unroll
    for (int ks = 0; ks < 8; ks++){
      const int kk = ks*32 + q*8;
      const int rk = kk >> 6;
      const int c0 = kk & 63;
      bf16x8 af2[2], bv[4];
      #pragma unroll
      for (int i = 0; i < 2; i++)
        af2[i] = *(const bf16x8*)(Sb + (64*wv + 16*i + m)*256 + kk);
      #pragma unroll
      for (int jt = 0; jt < 4; jt++)
        bv[jt] = *(const bf16x8*)&XL[(rk << 6) + 16*jt + m][c0];
      #pragma unroll
      for (int i = 0; i < 2; i++)
        #pragma unroll
        for (int jt = 0; jt < 4; jt++)
          aT[i][jt] = __builtin_amdgcn_mfma_f32_16x16x32_bf16(af2[i], bv[jt], aT[i][jt], 0, 0, 0);
    }
    #pragma unroll
    for (int i = 0; i < 2; i++)
      #pragma unroll
      for (int jt = 0; jt < 4; jt++){
        tp0[i][jt].x = (unsigned)f2bf(aT[i][jt][0]) | ((unsigned)f2bf(aT[i][jt][1]) << 16);
        tp0[i][jt].y = (unsigned)f2bf(aT[i][jt][2]) | ((unsigned)f2bf(aT[i][jt][3]) << 16);
      }
  }

  // ---- pass B: it = 2,3 (aTb stays live across the barrier) ----
  f32x4 aTb[2][4];
  #pragma unroll
  for (int i = 0; i < 2; i++)
    #pragma unroll
    for (int j = 0; j < 4; j++) aTb[i][j] = vzero;
  #pragma unroll
  for (int ks = 0; ks < 8; ks++){
    const int kk = ks*32 + q*8;
    const int rk = kk >> 6;
    const int c0 = kk & 63;
    bf16x8 af2[2], bv[4];
    #pragma unroll
    for (int i = 0; i < 2; i++)
      af2[i] = *(const bf16x8*)(Sb + (64*wv + 16*(2 + i) + m)*256 + kk);
    #pragma unroll
    for (int jt = 0; jt < 4; jt++)
      bv[jt] = *(const bf16x8*)&XL[(rk << 6) + 16*jt + m][c0];
    #pragma unroll
    for (int i = 0; i < 2; i++)
      #pragma unroll
      for (int jt = 0; jt < 4; jt++)
        aTb[i][jt] = __builtin_amdgcn_mfma_f32_16x16x32_bf16(af2[i], bv[jt], aTb[i][jt], 0, 0, 0);
  }
  __syncthreads();   // all waves done reading C2 before T' overwrites XL

  // T' -> XL wave-own rows [64wv + jl][c' = i'_local]
  #pragma unroll
  for (int i = 0; i < 2; i++)
    #pragma unroll
    for (int jt = 0; jt < 4; jt++)
      *(uint2*)&XL[64*wv + 16*jt + m][16*i + 4*q] = tp0[i][jt];
  #pragma unroll
  for (int i = 0; i < 2; i++)
    #pragma unroll
    for (int jt = 0; jt < 4; jt++){
      uint2 pk;
      pk.x = (unsigned)f2bf(aTb[i][jt][0]) | ((unsigned)f2bf(aTb[i][jt][1]) << 16);
      pk.y = (unsigned)f2bf(aTb[i][jt][2]) | ((unsigned)f2bf(aTb[i][jt][3]) << 16);
      *(uint2*)&XL[64*wv + 16*jt + m][16*(2 + i) + 4*q] = pk;
    }

  // GEMM2: out_pre[s][cout] = sum_c' T[s][c'] * wO[cout][c'] — two stl-halves
  bf16x8 wfrO[4][2];
  #pragma unroll
  for (int ct = 0; ct < 4; ct++)
    #pragma unroll
    for (int k2 = 0; k2 < 2; k2++)
      wfrO[ct][k2] = cvt8(wO + (16*ct + m)*64 + k2*32 + q*8);

  float sOv[4], tOv[4];
  #pragma unroll
  for (int ct = 0; ct < 4; ct++){ sOv[ct] = sOl[16*ct + m]; tOv[ct] = tOl[16*ct + m]; }

  const size_t outB = ((size_t)b << 22);
  #pragma unroll
  for (int h = 0; h < 2; h++){
    f32x4 a2[2][4];
    #pragma unroll
    for (int i = 0; i < 2; i++)
      #pragma unroll
      for (int j = 0; j < 4; j++) a2[i][j] = vzero;
    #pragma unroll
    for (int k2 = 0; k2 < 2; k2++)
      #pragma unroll
      for (int s2 = 0; s2 < 2; s2++){
        const int stl = 2*h + s2;
        const bf16x8 afT = *(const bf16x8*)&XL[64*wv + 16*stl + m][k2*32 + q*8];
        #pragma unroll
        for (int ct = 0; ct < 4; ct++)
          a2[s2][ct] = __builtin_amdgcn_mfma_f32_16x16x32_bf16(afT, wfrO[ct][k2], a2[s2][ct], 0, 0, 0);
      }
    #pragma unroll
    for (int s2 = 0; s2 < 2; s2++)
      #pragma unroll
      for (int ct = 0; ct < 4; ct++){
        const int stl = 2*h + s2;
        const int cout = 16*ct + m;
        const int ng0 = (wv << 14) + j0 + 16*stl + 4*q;   // STRIP mapping
        float* po = out + outB + ((size_t)cout << 16) + ng0;
        float4 pk;
        pk.x = c2r[stl][ct][0] + lrelu(a2[s2][ct][0] * sOv[ct] + tOv[ct]);
        pk.y = c2r[stl][ct][1] + lrelu(a2[s2][ct][1] * sOv[ct] + tOv[ct]);
        pk.z = c2r[stl][ct][2] + lrelu(a2[s2][ct][2] * sOv[ct] + tOv[ct]);
        pk.w = c2r[stl][ct][3] + lrelu(a2[s2][ct][3] * sOv[ct] + tOv[ct]);
        *(float4*)po = pk;
      }
  }
}

extern "C" void kernel_launch(void* const* d_in, const int* in_sizes, int n_in,
                              void* d_out, int out_size, void* d_ws, size_t ws_size,
                              hipStream_t stream) {
  const float* x   = (const float*)d_in[0];
  const float* w1  = (const float*)d_in[1];
  const float* b1  = (const float*)d_in[2];
  const float* g1  = (const float*)d_in[3];
  const float* be1 = (const float*)d_in[4];
  const float* m1  = (const float*)d_in[5];
  const float* v1  = (const float*)d_in[6];
  const float* wA  = (const float*)d_in[7];
  const float* bA  = (const float*)d_in[8];
  const float* gA  = (const float*)d_in[9];
  const float* beA = (const float*)d_in[10];
  const float* mA  = (const float*)d_in[11];
  const float* vA  = (const float*)d_in[12];
  const float* wO  = (const float*)d_in[13];
  const float* bO  = (const float*)d_in[14];
  const float* gO  = (const float*)d_in[15];
  const float* beO = (const float*)d_in[16];
  const float* mO  = (const float*)d_in[17];
  const float* vO  = (const float*)d_in[18];

  float* out = (float*)d_out;

  // ws layout (bytes): C1 fp32 [0,2M) | Ssum2 bf16 [6M,7M)
  // Gram partials P (16MB) live in d_out[0,16MB) — free until k3 overwrites out.
  char* ws = (char*)d_ws;
  float* C1             = (float*)(ws);
  unsigned short* Ssum2 = (unsigned short*)(ws + (size_t)(6u << 20));

  k1_c1<<<dim3(1024), dim3(256), 0, stream>>>(x, w1, b1, g1, be1, m1, v1, C1);
  k2_gram<<<dim3(1024), dim3(256), 0, stream>>>(C1, out);
  k2_softmax<<<dim3(2048), dim3(256), 0, stream>>>(out, out + 33554432u, out + 34078720u, Ssum2);
  k3_main<<<dim3(2048), dim3(256), 0, stream>>>(x, wA, bA, gA, beA, mA, vA, Ssum2,
                                                wO, bO, gO, beO, mO, vO, out);
}

// Round 8
// 366.059 us; speedup vs baseline: 1.2225x; 1.0960x over previous
//
#include <hip/hip_runtime.h>

// SOAM fused pipeline v9, MI355X gfx950.
// k3 ledger (final): v2's 64-col strip tile needs ~210 regs -> 2 blocks/CU is structural.
//   (256,3) spills (v4: +137MB, v8: +204MB HBM scratch traffic); j-tile 32 latency-collapses
//   (v6 162us); 512-thr blocks quantize to 1 blk/CU (v5 178us). v9 reverts k3 to the
//   proven v2 kernel verbatim (104us, FETCH 74MB / WRITE 139MB, occ 20%).
// New in v9: MFMA Gram. k1 emits C1 as bf16 hi/lo split (hi=bf16(v), lo=bf16(v-hi)) in
//   row-major AND transposed layouts (4 x 1MB in ws); k2_gram computes
//   G = hi.hi^T + hi.lo^T + lo.hi^T per 16x16 MFMA tile, LDS-free, operands straight from
//   L2 (same 512B-pitch 16B-frag pattern as k3's Ssum reads). hi/lo compensation keeps
//   G accurate to ~1e-3 (dropped lo.lo ~ 2^-18) => S1/S2 numerics unchanged vs fp32.
//   G1 symmetric, G2 symmetric => row/col conventions verified against reference.
// B=8, C=64, H=W=256. Identity: R1==R2 => R3+R4 = (S1+S2)@R. Permutations
// i'=(i&3)*64+(i>>2), k^=(k&3)*64+(k>>2) applied to Ssum when writing it.
// ws: C1hi [0,1M) | C1lo [1,2M) | C1Thi [2,3M) | C1Tlo [3,4M) | Ssum2 bf16 [6M,7M).
// G fp32 (16MB) in d_out[0,16MB) — free until k3 overwrites out.

#define EPS 1e-5f

typedef __attribute__((ext_vector_type(8))) short bf16x8;
typedef __attribute__((ext_vector_type(4))) float f32x4;

__device__ __forceinline__ unsigned short f2bf(float f){
  union { float f; unsigned int u; } a; a.f = f;
  return (unsigned short)((a.u + 0x7fffu + ((a.u >> 16) & 1u)) >> 16);
}
__device__ __forceinline__ float bf2f(unsigned short u){
  union { unsigned int i; float f; } v; v.i = ((unsigned int)u) << 16; return v.f;
}
__device__ __forceinline__ float lrelu(float y){ return y >= 0.f ? y : 0.2f * y; }
__device__ __forceinline__ bf16x8 cvt8(const float* p){
  float4 a = *(const float4*)p;
  float4 b = *(const float4*)(p + 4);
  bf16x8 r;
  r[0] = (short)f2bf(a.x); r[1] = (short)f2bf(a.y); r[2] = (short)f2bf(a.z); r[3] = (short)f2bf(a.w);
  r[4] = (short)f2bf(b.x); r[5] = (short)f2bf(b.y); r[6] = (short)f2bf(b.z); r[7] = (short)f2bf(b.w);
  return r;
}

// ---------------- K1: C1 = lrelu(BN(x . w1)) -> bf16 hi/lo, row + transposed layouts ----------------
// grid 512 (b*64 + tile1024), block 256, float4/thread.
__global__ __launch_bounds__(256) void k1_c1(
    const float* __restrict__ x, const float* __restrict__ w1,
    const float* __restrict__ pb1, const float* __restrict__ pg1,
    const float* __restrict__ pbe1, const float* __restrict__ pm1,
    const float* __restrict__ pv1,
    unsigned short* __restrict__ C1hi, unsigned short* __restrict__ C1lo,
    unsigned short* __restrict__ C1Thi, unsigned short* __restrict__ C1Tlo)
{
  const int blk = blockIdx.x;
  const int b = blk >> 6;
  const int n0 = (blk & 63) << 10;
  const int t = threadIdx.x;
  __shared__ float w1s[64];
  if (t < 64) w1s[t] = w1[t];
  __syncthreads();
  const float* xb = x + ((size_t)b << 22);
  const int n = n0 + (t << 2);
  float4 d = {0.f, 0.f, 0.f, 0.f};
  #pragma unroll 16
  for (int c = 0; c < 64; c++){
    const float4 xv = *(const float4*)(xb + ((size_t)c << 16) + n);
    const float wv = w1s[c];
    d.x = fmaf(xv.x, wv, d.x); d.y = fmaf(xv.y, wv, d.y);
    d.z = fmaf(xv.z, wv, d.z); d.w = fmaf(xv.w, wv, d.w);
  }
  const float s1 = pg1[0] * rsqrtf(pv1[0] + EPS);
  const float t1 = (pb1[0] - pm1[0]) * s1 + pbe1[0];
  float o[4];
  o[0] = lrelu(d.x * s1 + t1); o[1] = lrelu(d.y * s1 + t1);
  o[2] = lrelu(d.z * s1 + t1); o[3] = lrelu(d.w * s1 + t1);

  unsigned short hi[4], lo[4];
  #pragma unroll
  for (int e = 0; e < 4; e++){
    hi[e] = f2bf(o[e]);
    lo[e] = f2bf(o[e] - bf2f(hi[e]));
  }
  const int base = (b << 16) + n;
  // row-major stores (8B packed)
  uint2 ph, pl;
  ph.x = (unsigned)hi[0] | ((unsigned)hi[1] << 16);
  ph.y = (unsigned)hi[2] | ((unsigned)hi[3] << 16);
  pl.x = (unsigned)lo[0] | ((unsigned)lo[1] << 16);
  pl.y = (unsigned)lo[2] | ((unsigned)lo[3] << 16);
  *(uint2*)(C1hi + base) = ph;
  *(uint2*)(C1lo + base) = pl;
  // transposed scatter: C1T[b][w][h]
  const int h = n >> 8, w = n & 255;
  #pragma unroll
  for (int e = 0; e < 4; e++){
    C1Thi[(b << 16) + (w + e)*256 + h] = hi[e];
    C1Tlo[(b << 16) + (w + e)*256 + h] = lo[e];
  }
}

// ---------------- K2a: MFMA Gram, LDS-free, hi/lo compensated ----------------
// grid 256: bx = b(3b) | which(1b) | tile(4b); block = 4 waves, wave = 32x32 quadrant.
// which=0: G1[h][h'] = sum_w C1[h][w]C1[h'][w]  (operands = C1 rows)
// which=1: G2[w][w'] = sum_h C1T[w][h]C1T[w'][h] (operands = C1T rows)
__global__ __launch_bounds__(256) void k2_gram(
    const unsigned short* __restrict__ C1hi, const unsigned short* __restrict__ C1lo,
    const unsigned short* __restrict__ C1Thi, const unsigned short* __restrict__ C1Tlo,
    float* __restrict__ G)
{
  const int bx = blockIdx.x;
  const int tile = bx & 15;
  const int which = (bx >> 4) & 1;
  const int b = bx >> 5;
  const int t = threadIdx.x;
  const int lane = t & 63, wv = t >> 6;
  const int m = lane & 15, q = lane >> 4;
  const int ibase = ((tile >> 2) << 6) + 32*(wv >> 1);
  const int jbase = ((tile & 3) << 6) + 32*(wv & 1);

  const unsigned short* Phi = (which ? C1Thi : C1hi) + ((size_t)b << 16);
  const unsigned short* Plo = (which ? C1Tlo : C1lo) + ((size_t)b << 16);

  const f32x4 vzero = {0.f, 0.f, 0.f, 0.f};
  f32x4 acc[2][2];
  #pragma unroll
  for (int i = 0; i < 2; i++)
    #pragma unroll
    for (int j = 0; j < 2; j++) acc[i][j] = vzero;

  #pragma unroll
  for (int ks = 0; ks < 8; ks++){
    const int kk = ks*32 + q*8;
    bf16x8 ah[2], al[2], bh[2], bl[2];
    #pragma unroll
    for (int it = 0; it < 2; it++){
      ah[it] = *(const bf16x8*)(Phi + (ibase + 16*it + m)*256 + kk);
      al[it] = *(const bf16x8*)(Plo + (ibase + 16*it + m)*256 + kk);
    }
    #pragma unroll
    for (int jt = 0; jt < 2; jt++){
      bh[jt] = *(const bf16x8*)(Phi + (jbase + 16*jt + m)*256 + kk);
      bl[jt] = *(const bf16x8*)(Plo + (jbase + 16*jt + m)*256 + kk);
    }
    #pragma unroll
    for (int it = 0; it < 2; it++)
      #pragma unroll
      for (int jt = 0; jt < 2; jt++){
        acc[it][jt] = __builtin_amdgcn_mfma_f32_16x16x32_bf16(ah[it], bh[jt], acc[it][jt], 0, 0, 0);
        acc[it][jt] = __builtin_amdgcn_mfma_f32_16x16x32_bf16(ah[it], bl[jt], acc[it][jt], 0, 0, 0);
        acc[it][jt] = __builtin_amdgcn_mfma_f32_16x16x32_bf16(al[it], bh[jt], acc[it][jt], 0, 0, 0);
      }
  }

  float* Go = G + ((size_t)(which*8 + b) << 16);
  #pragma unroll
  for (int it = 0; it < 2; it++)
    #pragma unroll
    for (int jt = 0; jt < 2; jt++)
      #pragma unroll
      for (int r = 0; r < 4; r++)
        Go[(ibase + 16*it + 4*q + r)*256 + jbase + 16*jt + m] = acc[it][jt][r];
}

// ---------------- K2b: row softmax of G1,G2 -> S1,S2 (fp32, d_out) + permuted Ssum (bf16, ws) ----------------
__global__ __launch_bounds__(256) void k2_softmax(const float* __restrict__ G,
    float* __restrict__ S1o, float* __restrict__ S2o,
    unsigned short* __restrict__ Ssum2)
{
  const int bx = blockIdx.x;
  const int b = bx >> 8, i = bx & 255;
  const int j = threadIdx.x;
  const float v1 = G[((size_t)b << 16) + i*256 + j];
  const float v2 = G[((size_t)(8 + b) << 16) + i*256 + j];
  __shared__ float sm[4], sm2[4], ss[4], ss2[4];
  float a1 = v1, a2 = v2;
  #pragma unroll
  for (int off = 32; off > 0; off >>= 1){
    a1 = fmaxf(a1, __shfl_xor(a1, off));
    a2 = fmaxf(a2, __shfl_xor(a2, off));
  }
  const int wv = j >> 6;
  if ((j & 63) == 0){ sm[wv] = a1; sm2[wv] = a2; }
  __syncthreads();
  const float m1v = fmaxf(fmaxf(sm[0], sm[1]), fmaxf(sm[2], sm[3]));
  const float m2v = fmaxf(fmaxf(sm2[0], sm2[1]), fmaxf(sm2[2], sm2[3]));
  float e1 = __expf(v1 - m1v), e2 = __expf(v2 - m2v);
  float s1 = e1, s2 = e2;
  #pragma unroll
  for (int off = 32; off > 0; off >>= 1){
    s1 += __shfl_xor(s1, off);
    s2 += __shfl_xor(s2, off);
  }
  if ((j & 63) == 0){ ss[wv] = s1; ss2[wv] = s2; }
  __syncthreads();
  const float d1 = ss[0]+ss[1]+ss[2]+ss[3];
  const float d2 = ss2[0]+ss2[1]+ss2[2]+ss2[3];
  const float S1v = e1 / d1, S2v = e2 / d2;
  S1o[((size_t)b << 16) + i*256 + j] = S1v;
  S2o[((size_t)b << 16) + i*256 + j] = S2v;
  const int ip = ((i & 3) << 6) | (i >> 2);
  const int kp = ((j & 3) << 6) | (j >> 2);
  Ssum2[((size_t)b << 16) + ip*256 + kp] = f2bf(S1v + S2v);
}

// ---------------- K3: v2-proven. stage x->C2 (MFMA, direct gather) -> T' -> convO -> out ----------------
// grid 2048 (b*256 + coltile j0), block 256 = 4 waves, STRIP mapping, 2 blocks/CU.
// ~210 regs structural; do NOT bound below (256,2): (256,3)/(256,4) spill (v4/v8).
__global__ __launch_bounds__(256, 2) void k3_main(
    const float* __restrict__ x,
    const float* __restrict__ wA, const float* __restrict__ pbA,
    const float* __restrict__ pgA, const float* __restrict__ pbeA,
    const float* __restrict__ pmA, const float* __restrict__ pvA,
    const unsigned short* __restrict__ Ssum2,
    const float* __restrict__ wO, const float* __restrict__ pbO,
    const float* __restrict__ pgO, const float* __restrict__ pbeO,
    const float* __restrict__ pmO, const float* __restrict__ pvO,
    float* __restrict__ out)
{
  __shared__ unsigned short XL[256][72];     // bf16 [s = 64*wv + jl][c], +8 pad
  __shared__ unsigned short T_lds[256][72];  // bf16 [s][c_T]
  __shared__ float sAl[64], tAl[64], sOl[64], tOl[64];
  const int blk = blockIdx.x;
  const int b  = blk >> 8;
  const int j0 = (blk & 255) << 6;
  const int t = threadIdx.x;
  const int lane = t & 63, wv = t >> 6;
  const int m = lane & 15, q = lane >> 4;

  if (t < 64){
    const float sA = pgA[t] * rsqrtf(pvA[t] + EPS);
    sAl[t] = sA; tAl[t] = (pbA[t] - pmA[t]) * sA + pbeA[t];
    const float sO = pgO[t] * rsqrtf(pvO[t] + EPS);
    sOl[t] = sO; tOl[t] = (pbO[t] - pmO[t]) * sO + pbeO[t];
  }
  __syncthreads();

  float sAv[4], tAv[4];
  #pragma unroll
  for (int ot = 0; ot < 4; ot++){ sAv[ot] = sAl[16*ot + m]; tAv[ot] = tAl[16*ot + m]; }

  bf16x8 wfrA[4][2];
  #pragma unroll
  for (int ot = 0; ot < 4; ot++)
    #pragma unroll
    for (int ks = 0; ks < 2; ks++)
      wfrA[ot][ks] = cvt8(wA + (16*ot + m)*64 + ks*32 + q*8);

  const f32x4 vzero = {0.f, 0.f, 0.f, 0.f};
  f32x4 c2r[4][4];   // fp32 C2 residual, held to the epilogue
  #pragma unroll
  for (int i = 0; i < 4; i++)
    #pragma unroll
    for (int j = 0; j < 4; j++) c2r[i][j] = vzero;

  // MFMA1 via direct gather: wave wv's strip = (wv<<14) + j0 + [0,64)
  const float* xb = x + ((size_t)b << 22) + (wv << 14) + j0;
  #pragma unroll
  for (int ks = 0; ks < 2; ks++)
    #pragma unroll
    for (int nt = 0; nt < 4; nt++){
      bf16x8 af;
      #pragma unroll
      for (int u = 0; u < 8; u++){
        const int c = ks*32 + q*8 + u;
        af[u] = (short)f2bf(xb[((size_t)c << 16) + 16*nt + m]);
      }
      #pragma unroll
      for (int ot = 0; ot < 4; ot++)
        c2r[nt][ot] = __builtin_amdgcn_mfma_f32_16x16x32_bf16(af, wfrA[ot][ks], c2r[nt][ot], 0, 0, 0);
    }

  // BN + LReLU (fp32 residual) + bf16 C2 into XL (wave-own rows)
  #pragma unroll
  for (int nt = 0; nt < 4; nt++)
    #pragma unroll
    for (int ot = 0; ot < 4; ot++){
      #pragma unroll
      for (int r = 0; r < 4; r++){
        const float v = lrelu(c2r[nt][ot][r] * sAv[ot] + tAv[ot]);
        c2r[nt][ot][r] = v;
        XL[64*wv + 16*nt + 4*q + r][16*ot + m] = f2bf(v);
      }
    }
  __syncthreads();

  // GEMM1: T'[i'][jl] = sum_k^ Ssum2[i'][k^] * XL[(k^>>6)*64 + jl][k^&63]
  const unsigned short* Sb = Ssum2 + ((size_t)b << 16);
  f32x4 accT[4][4];
  #pragma unroll
  for (int i = 0; i < 4; i++)
    #pragma unroll
    for (int j = 0; j < 4; j++) accT[i][j] = vzero;

  #pragma unroll
  for (int ks = 0; ks < 8; ks++){
    const int kk = ks*32 + q*8;
    const int rk = kk >> 6;
    const int c0 = kk & 63;
    bf16x8 af[4], bv[4];
    #pragma unroll
    for (int it = 0; it < 4; it++)
      af[it] = *(const bf16x8*)(Sb + (64*wv + 16*it + m)*256 + kk);
    #pragma unroll
    for (int jt = 0; jt < 4; jt++)
      bv[jt] = *(const bf16x8*)&XL[(rk << 6) + 16*jt + m][c0];
    #pragma unroll
    for (int it = 0; it < 4; it++)
      #pragma unroll
      for (int jt = 0; jt < 4; jt++)
        accT[it][jt] = __builtin_amdgcn_mfma_f32_16x16x32_bf16(af[it], bv[jt], accT[it][jt], 0, 0, 0);
  }

  // T' -> T_lds wave-own rows [64wv + jl][c' = i'_local]; same wave reads back.
  #pragma unroll
  for (int it = 0; it < 4; it++)
    #pragma unroll
    for (int jt = 0; jt < 4; jt++){
      uint2 pk;
      pk.x = (unsigned)f2bf(accT[it][jt][0]) | ((unsigned)f2bf(accT[it][jt][1]) << 16);
      pk.y = (unsigned)f2bf(accT[it][jt][2]) | ((unsigned)f2bf(accT[it][jt][3]) << 16);
      *(uint2*)&T_lds[64*wv + 16*jt + m][16*it + 4*q] = pk;
    }

  // GEMM2: out_pre[s][cout] = sum_c' T[s][c'] * wO[cout][c']
  bf16x8 wfrO[4][2];
  #pragma unroll
  for (int ct = 0; ct < 4; ct++)
    #pragma unroll
    for (int k2 = 0; k2 < 2; k2++)
      wfrO[ct][k2] = cvt8(wO + (16*ct + m)*64 + k2*32 + q*8);

  f32x4 acc2[4][4];
  #pragma unroll
  for (int i = 0; i < 4; i++)
    #pragma unroll
    for (int j = 0; j < 4; j++) acc2[i][j] = vzero;

  #pragma unroll
  for (int k2 = 0; k2 < 2; k2++)
    #pragma unroll
    for (int stl = 0; stl < 4; stl++){
      const bf16x8 afT = *(const bf16x8*)&T_lds[64*wv + 16*stl + m][k2*32 + q*8];
      #pragma unroll
      for (int ct = 0; ct < 4; ct++)
        acc2[stl][ct] = __builtin_amdgcn_mfma_f32_16x16x32_bf16(afT, wfrO[ct][k2], acc2[stl][ct], 0, 0, 0);
    }

  float sOv[4], tOv[4];
  #pragma unroll
  for (int ct = 0; ct < 4; ct++){ sOv[ct] = sOl[16*ct + m]; tOv[ct] = tOl[16*ct + m]; }

  const size_t outB = ((size_t)b << 22);
  #pragma unroll
  for (int stl = 0; stl < 4; stl++)
    #pragma unroll
    for (int ct = 0; ct < 4; ct++){
      const int cout = 16*ct + m;
      const int ng0 = (wv << 14) + j0 + 16*stl + 4*q;   // STRIP mapping
      float* po = out + outB + ((size_t)cout << 16) + ng0;
      float4 pk;
      pk.x = c2r[stl][ct][0] + lrelu(acc2[stl][ct][0] * sOv[ct] + tOv[ct]);
      pk.y = c2r[stl][ct][1] + lrelu(acc2[stl][ct][1] * sOv[ct] + tOv[ct]);
      pk.z = c2r[stl][ct][2] + lrelu(acc2[stl][ct][2] * sOv[ct] + tOv[ct]);
      pk.w = c2r[stl][ct][3] + lrelu(acc2[stl][ct][3] * sOv[ct] + tOv[ct]);
      *(float4*)po = pk;
    }
}

extern "C" void kernel_launch(void* const* d_in, const int* in_sizes, int n_in,
                              void* d_out, int out_size, void* d_ws, size_t ws_size,
                              hipStream_t stream) {
  const float* x   = (const float*)d_in[0];
  const float* w1  = (const float*)d_in[1];
  const float* b1  = (const float*)d_in[2];
  const float* g1  = (const float*)d_in[3];
  const float* be1 = (const float*)d_in[4];
  const float* m1  = (const float*)d_in[5];
  const float* v1  = (const float*)d_in[6];
  const float* wA  = (const float*)d_in[7];
  const float* bA  = (const float*)d_in[8];
  const float* gA  = (const float*)d_in[9];
  const float* beA = (const float*)d_in[10];
  const float* mA  = (const float*)d_in[11];
  const float* vA  = (const float*)d_in[12];
  const float* wO  = (const float*)d_in[13];
  const float* bO  = (const float*)d_in[14];
  const float* gO  = (const float*)d_in[15];
  const float* beO = (const float*)d_in[16];
  const float* mO  = (const float*)d_in[17];
  const float* vO  = (const float*)d_in[18];

  float* out = (float*)d_out;

  // ws layout (bytes): C1hi [0,1M) | C1lo [1,2M) | C1Thi [2,3M) | C1Tlo [3,4M) | Ssum2 [6M,7M)
  // G fp32 (16MB) lives in d_out[0,16MB) — free until k3 overwrites out.
  char* ws = (char*)d_ws;
  unsigned short* C1hi  = (unsigned short*)(ws);
  unsigned short* C1lo  = (unsigned short*)(ws + (size_t)(1u << 20));
  unsigned short* C1Thi = (unsigned short*)(ws + (size_t)(2u << 20));
  unsigned short* C1Tlo = (unsigned short*)(ws + (size_t)(3u << 20));
  unsigned short* Ssum2 = (unsigned short*)(ws + (size_t)(6u << 20));

  k1_c1<<<dim3(512), dim3(256), 0, stream>>>(x, w1, b1, g1, be1, m1, v1,
                                             C1hi, C1lo, C1Thi, C1Tlo);
  k2_gram<<<dim3(256), dim3(256), 0, stream>>>(C1hi, C1lo, C1Thi, C1Tlo, out);
  k2_softmax<<<dim3(2048), dim3(256), 0, stream>>>(out, out + 33554432u, out + 34078720u, Ssum2);
  k3_main<<<dim3(2048), dim3(256), 0, stream>>>(x, wA, bA, gA, beA, mA, vA, Ssum2,
                                                wO, bO, gO, beO, mO, vO, out);
}